// Round 11
// baseline (303.103 us; speedup 1.0000x reference)
//
#include <hip/hip_runtime.h>
#include <cstdint>
#include <cmath>

#define Q_ 300
#define C_ 80
#define QC (Q_ * C_)
#define K_ 300
#define HM 160
#define WM 160
#define NBUCK 8192
#define CAND 2048
#define TOPK_THREADS 512

typedef float f32x4_t __attribute__((ext_vector_type(4)));

// -------- Kernel 1: per-batch top-K over sigmoid(logits) --------
// Histogram-select + rank-by-counting (keys unique -> rank is a permutation).
__global__ __launch_bounds__(TOPK_THREADS) void topk_kernel(
    const float* __restrict__ logits,   // [B,Q,C]
    const float* __restrict__ boxes_in, // [B,Q,4] cxcywh
    float* __restrict__ out,            // labels[B,K] | boxes[B,K,4] | scores[B,K]
    int* __restrict__ meta,             // [B*K,5] : q, x1,y1,x2,y2
    int B, int S)
{
    int b = blockIdx.x;
    int tid = threadIdx.x;
    __shared__ unsigned int hist[NBUCK];
    __shared__ unsigned int csum[TOPK_THREADS];
    __shared__ unsigned long long cand[CAND];
    __shared__ unsigned long long sorted[K_];
    __shared__ unsigned int candCount;
    __shared__ int bstar;

    for (int i = tid; i < NBUCK; i += TOPK_THREADS) hist[i] = 0u;
    if (tid == 0) { candCount = 0u; bstar = 0; }
    __syncthreads();

    const float* lg = logits + (size_t)b * QC;
    const f32x4_t* lg4 = reinterpret_cast<const f32x4_t*>(lg);

    // histogram over top 13 bits of score bit pattern (monotone for positive floats)
    for (int j = tid; j < QC / 4; j += TOPK_THREADS) {
        f32x4_t v4 = lg4[j];
#pragma unroll
        for (int c = 0; c < 4; ++c) {
            float s = 1.0f / (1.0f + expf(-v4[c]));
            unsigned int bits = __float_as_uint(s);
            atomicAdd(&hist[bits >> 19], 1u);
        }
    }
    __syncthreads();

    // per-thread chunk of 16 buckets -> chunk sum
    unsigned int chunkSum = 0u;
    int base = tid * (NBUCK / TOPK_THREADS);
#pragma unroll
    for (int j = 0; j < NBUCK / TOPK_THREADS; ++j) chunkSum += hist[base + j];
    csum[tid] = chunkSum;
    __syncthreads();

    // suffix-inclusive scan: csum[t] = sum_{t'>=t}
    for (int off = 1; off < TOPK_THREADS; off <<= 1) {
        unsigned int v = (tid + off < TOPK_THREADS) ? csum[tid + off] : 0u;
        __syncthreads();
        csum[tid] += v;
        __syncthreads();
    }

    // locate threshold bucket: cumAbove < K <= cumAbove + count
    unsigned int run = (tid < TOPK_THREADS - 1) ? csum[tid + 1] : 0u;
    for (int j = NBUCK / TOPK_THREADS - 1; j >= 0; --j) {
        unsigned int c = hist[base + j];
        if (run < (unsigned)K_ && run + c >= (unsigned)K_) bstar = base + j;  // unique writer
        run += c;
    }
    __syncthreads();
    int bs = bstar;

    // gather candidates; key = score_bits<<32 | (UINT_MAX - idx)
    for (int j = tid; j < QC / 4; j += TOPK_THREADS) {
        f32x4_t v4 = lg4[j];
#pragma unroll
        for (int c = 0; c < 4; ++c) {
            int i = j * 4 + c;
            float s = 1.0f / (1.0f + expf(-v4[c]));
            unsigned int bits = __float_as_uint(s);
            if ((int)(bits >> 19) >= bs) {
                unsigned int pos = atomicAdd(&candCount, 1u);
                if (pos < CAND)
                    cand[pos] = ((unsigned long long)bits << 32)
                              | (unsigned long long)(0xFFFFFFFFu - (unsigned int)i);
            }
        }
    }
    __syncthreads();
    unsigned int n = candCount; if (n > CAND) n = CAND;

    // rank-by-counting: LDS reads of cand[j] are lockstep -> broadcast, conflict-free.
    for (unsigned int i = tid; i < n; i += TOPK_THREADS) {
        unsigned long long ki = cand[i];
        unsigned int rank = 0;
        for (unsigned int j = 0; j < n; ++j)
            rank += (cand[j] > ki) ? 1u : 0u;
        if (rank < (unsigned)K_) sorted[rank] = ki;
    }
    __syncthreads();

    // emit
    float Sf = (float)S;
    float* out_labels = out;
    float* out_boxes  = out + (size_t)B * K_;
    float* out_scores = out + (size_t)B * K_ * 5;
    if (tid < K_) {
        unsigned long long key = sorted[tid];
        unsigned int bits = (unsigned int)(key >> 32);
        unsigned int idx  = 0xFFFFFFFFu - (unsigned int)(key & 0xFFFFFFFFull);
        int label = (int)(idx % C_);
        int q     = (int)(idx / C_);
        const float* bx = boxes_in + ((size_t)b * Q_ + q) * 4;
        float cx = bx[0], cy = bx[1], bw = bx[2], bh = bx[3];
        float x1 = (cx - bw * 0.5f) * Sf;
        float y1 = (cy - bh * 0.5f) * Sf;
        float x2 = (cx + bw * 0.5f) * Sf;
        float y2 = (cy + bh * 0.5f) * Sf;
        int o = b * K_ + tid;
        out_labels[o] = (float)label;
        out_scores[o] = __uint_as_float(bits);
        out_boxes[(size_t)o * 4 + 0] = x1;
        out_boxes[(size_t)o * 4 + 1] = y1;
        out_boxes[(size_t)o * 4 + 2] = x2;
        out_boxes[(size_t)o * 4 + 3] = y2;
        int xi1 = min(max((int)truncf(x1), 0), S);
        int yi1 = min(max((int)truncf(y1), 0), S);
        int xi2 = min(max((int)truncf(x2), 0), S);
        int yi2 = min(max((int)truncf(y2), 0), S);
        meta[(size_t)o * 5 + 0] = q;
        meta[(size_t)o * 5 + 1] = xi1;
        meta[(size_t)o * 5 + 2] = yi1;
        meta[(size_t)o * 5 + 3] = xi2;
        meta[(size_t)o * 5 + 4] = yi2;
    }
}

// -------- Kernel 2 (S=512): LDS-staged rows; XCD-chunked; PLAIN stores; 8 blocks/CU --------
__global__ __launch_bounds__(256, 8) void mask_kernel_512(
    const float* __restrict__ masks,  // [B,Q,HM,WM]
    const int* __restrict__ meta,     // [B*K,5]
    float* __restrict__ out_masks,    // [B*K,512,512]
    int nwork)                        // B*K*16
{
    constexpr int S = 512;
    constexpr float ISC = 0.3125f;  // HM/S exact
    __shared__ float lds[12 * WM];  // up to 12 source rows

    int bid = blockIdx.x;
    int chunk = nwork >> 3;                    // nwork % 8 == 0
    int work = (bid & 7) * chunk + (bid >> 3); // XCD-chunked, bijective
    int bk = work >> 4;
    int yt = work & 15;

    int b = bk / K_;
    const int* m = meta + (size_t)bk * 5;
    int q  = m[0];
    int x1 = m[1], y1 = m[2], x2 = m[3], y2 = m[4];
    const float* src = masks + ((size_t)b * Q_ + q) * (HM * WM);
    float* dst = out_masks + (size_t)bk * S * S;
    int yb0 = yt << 5;  // 32 rows per block

    // Block-level fast path: whole 32-row stripe is zero
    bool stripeLive = (y1 < yb0 + 32) && (y2 > yb0) && (y1 < y2) &&
                      (x1 < x2) && (x1 < S) && (x2 > 0);
    if (!stripeLive) {
        f32x4_t z = (f32x4_t)(0.0f);
        f32x4_t* base2 = reinterpret_cast<f32x4_t*>(dst + (size_t)yb0 * S);
        for (int t = threadIdx.x; t < 32 * 128; t += 256)
            base2[t] = z;
        return;
    }

    // Stage the needed source rows into LDS (coalesced float4, once per block).
    int fFirst = (int)floorf((yb0 + 0.5f) * ISC - 0.5f);
    int fLast  = (int)floorf((yb0 + 31.5f) * ISC - 0.5f);
    int rowBase = max(fFirst, 0);
    int rowEnd  = min(fLast + 1, HM - 1);
    int nf4 = (rowEnd - rowBase + 1) * (WM / 4);
    {
        const f32x4_t* g4 = reinterpret_cast<const f32x4_t*>(masks + ((size_t)b * Q_ + q) * (HM * WM) + (size_t)rowBase * WM);
        f32x4_t* l4 = reinterpret_cast<f32x4_t*>(lds);
        for (int i = threadIdx.x; i < nf4; i += 256) l4[i] = g4[i];
    }
    __syncthreads();

    // 32 rows x 128 float4-chunks; wave-uniform row test, per-lane x-window test
    for (int t = threadIdx.x; t < 32 * 128; t += 256) {
        int ry = t >> 7;
        int xq = t & 127;
        int y  = yb0 + ry;
        int x0 = xq << 2;
        f32x4_t r = (f32x4_t)(0.0f);
        if (y >= y1 && y < y2 && x0 + 4 > x1 && x0 < x2) {
            float iy  = (y + 0.5f) * ISC - 0.5f;
            float fyf = floorf(iy);
            int   y0i = (int)fyf;
            float fy  = iy - fyf;
            int ya = max(y0i, 0);
            int yb = min(y0i + 1, HM - 1);
            const float* r0 = lds + (size_t)(ya - rowBase) * WM;
            const float* r1 = lds + (size_t)(yb - rowBase) * WM;
            float wy0 = 1.0f - fy, wy1 = fy;

            // 3-wide input window shared by the 4 pixels
            float ib  = (x0 + 0.5f) * ISC - 0.5f;
            int   fb  = (int)floorf(ib);
            int i0 = max(fb, 0);
            int i1 = min(fb + 1, WM - 1);
            int i2 = min(fb + 2, WM - 1);
            float a0 = r0[i0], a1 = r0[i1], a2 = r0[i2];
            float b0 = r1[i0], b1 = r1[i1], b2 = r1[i2];

            float v[4];
#pragma unroll
            for (int c = 0; c < 4; ++c) {
                int x = x0 + c;
                float vv = 0.0f;
                if (x >= x1 && x < x2) {
                    float ix  = (x + 0.5f) * ISC - 0.5f;
                    float fxf = floorf(ix);
                    int   x0i = (int)fxf;
                    float fx  = ix - fxf;
                    int o = x0i - fb;           // 0 or 1
                    float va = o ? a1 : a0;
                    float vb = o ? a2 : a1;
                    float wa = o ? b1 : b0;
                    float wb = o ? b2 : b1;
                    float wx0 = 1.0f - fx, wx1 = fx;
                    float top = wx0 * va + wx1 * vb;
                    float bot = wx0 * wa + wx1 * wb;
                    float val = wy0 * top + wy1 * bot;
                    vv = (val > 0.0f) ? 1.0f : 0.0f;
                }
                v[c] = vv;
            }
            r = (f32x4_t){v[0], v[1], v[2], v[3]};
        }
        *reinterpret_cast<f32x4_t*>(dst + (size_t)y * S + x0) = r;
    }
}

// -------- Generic fallback (round-1 validated path) --------
__global__ __launch_bounds__(256) void mask_kernel_generic(
    const float* __restrict__ masks,
    const int* __restrict__ meta,
    float* __restrict__ out_masks,
    int S, int rowsPerTile)
{
    int bk = blockIdx.x;
    int ytile = blockIdx.y;
    int b = bk / K_;
    const int* m = meta + (size_t)bk * 5;
    int q  = m[0];
    int x1 = m[1], y1 = m[2], x2 = m[3], y2 = m[4];
    const float* src = masks + ((size_t)b * Q_ + q) * (HM * WM);
    float* dst = out_masks + (size_t)bk * S * S;
    float inv_scale = (float)((double)HM / (double)S);

    int qx = S >> 2;
    int total = rowsPerTile * qx;
    for (int t = threadIdx.x; t < total; t += 256) {
        int ry = t / qx;
        int xq = t - ry * qx;
        int y  = ytile * rowsPerTile + ry;
        int x0 = xq << 2;
        float4 r = make_float4(0.0f, 0.0f, 0.0f, 0.0f);
        if (y >= y1 && y < y2) {
            float iy  = (y + 0.5f) * inv_scale - 0.5f;
            float fyf = floorf(iy);
            int   y0i = (int)fyf;
            float fy  = iy - fyf;
            int ya = max(y0i, 0);
            int yb = min(y0i + 1, HM - 1);
            const float* r0 = src + (size_t)ya * WM;
            const float* r1 = src + (size_t)yb * WM;
            float wy0 = 1.0f - fy, wy1 = fy;
            float v[4];
#pragma unroll
            for (int c = 0; c < 4; ++c) {
                int x = x0 + c;
                float vv = 0.0f;
                if (x >= x1 && x < x2) {
                    float ix  = (x + 0.5f) * inv_scale - 0.5f;
                    float fxf = floorf(ix);
                    int   x0i = (int)fxf;
                    float fx  = ix - fxf;
                    int xa = max(x0i, 0);
                    int xb = min(x0i + 1, WM - 1);
                    float wx0 = 1.0f - fx, wx1 = fx;
                    float top = wx0 * r0[xa] + wx1 * r0[xb];
                    float bot = wx0 * r1[xa] + wx1 * r1[xb];
                    float val = wy0 * top + wy1 * bot;
                    vv = (val > 0.0f) ? 1.0f : 0.0f;
                }
                v[c] = vv;
            }
            r = make_float4(v[0], v[1], v[2], v[3]);
        }
        *reinterpret_cast<float4*>(dst + (size_t)y * S + x0) = r;
    }
}

extern "C" void kernel_launch(void* const* d_in, const int* in_sizes, int n_in,
                              void* d_out, int out_size, void* d_ws, size_t ws_size,
                              hipStream_t stream) {
    const float* pred_logits = (const float*)d_in[0];
    const float* pred_boxes  = (const float*)d_in[1];
    const float* pred_masks  = (const float*)d_in[2];

    int B = in_sizes[0] / QC;
    long long mask_elems = (long long)out_size - (long long)B * K_ * 6;
    int S = (int)llroundf(sqrtf((float)(mask_elems / ((long long)B * K_))));
    if (S <= 0) S = 512;

    float* out = (float*)d_out;
    int* meta = (int*)d_ws;

    topk_kernel<<<dim3(B), dim3(TOPK_THREADS), 0, stream>>>(
        pred_logits, pred_boxes, out, meta, B, S);

    float* out_masks = out + (size_t)B * K_ * 6;
    if (S == 512) {
        int nwork = B * K_ * 16;  // divisible by 8
        mask_kernel_512<<<dim3(nwork), dim3(256), 0, stream>>>(
            pred_masks, meta, out_masks, nwork);
    } else {
        int rowsPerTile = 32;
        int ntile = (S + rowsPerTile - 1) / rowsPerTile;
        mask_kernel_generic<<<dim3(B * K_, ntile), dim3(256), 0, stream>>>(
            pred_masks, meta, out_masks, S, rowsPerTile);
    }
}

// Round 12
// 294.365 us; speedup vs baseline: 1.0297x; 1.0297x over previous
//
#include <hip/hip_runtime.h>
#include <cstdint>
#include <cmath>

#define Q_ 300
#define C_ 80
#define QC (Q_ * C_)
#define K_ 300
#define HM 160
#define WM 160
#define NBUCK 8192
#define CAND 2048
#define TOPK_THREADS 512

typedef float f32x4_t __attribute__((ext_vector_type(4)));

// -------- Kernel 1: per-batch top-K over sigmoid(logits) --------
// (round-10 validated: histogram-select + rank-by-counting, vectorized loads)
__global__ __launch_bounds__(TOPK_THREADS) void topk_kernel(
    const float* __restrict__ logits,   // [B,Q,C]
    const float* __restrict__ boxes_in, // [B,Q,4] cxcywh
    float* __restrict__ out,            // labels[B,K] | boxes[B,K,4] | scores[B,K]
    int* __restrict__ meta,             // [B*K,5] : q, x1,y1,x2,y2
    int B, int S)
{
    int b = blockIdx.x;
    int tid = threadIdx.x;
    __shared__ unsigned int hist[NBUCK];
    __shared__ unsigned int csum[TOPK_THREADS];
    __shared__ unsigned long long cand[CAND];
    __shared__ unsigned long long sorted[K_];
    __shared__ unsigned int candCount;
    __shared__ int bstar;

    for (int i = tid; i < NBUCK; i += TOPK_THREADS) hist[i] = 0u;
    if (tid == 0) { candCount = 0u; bstar = 0; }
    __syncthreads();

    const float* lg = logits + (size_t)b * QC;
    const f32x4_t* lg4 = reinterpret_cast<const f32x4_t*>(lg);

    // histogram over top 13 bits of score bit pattern (monotone for positive floats)
    for (int j = tid; j < QC / 4; j += TOPK_THREADS) {
        f32x4_t v4 = lg4[j];
#pragma unroll
        for (int c = 0; c < 4; ++c) {
            float s = 1.0f / (1.0f + expf(-v4[c]));
            unsigned int bits = __float_as_uint(s);
            atomicAdd(&hist[bits >> 19], 1u);
        }
    }
    __syncthreads();

    // per-thread chunk of 16 buckets -> chunk sum
    unsigned int chunkSum = 0u;
    int base = tid * (NBUCK / TOPK_THREADS);
#pragma unroll
    for (int j = 0; j < NBUCK / TOPK_THREADS; ++j) chunkSum += hist[base + j];
    csum[tid] = chunkSum;
    __syncthreads();

    // suffix-inclusive scan: csum[t] = sum_{t'>=t}
    for (int off = 1; off < TOPK_THREADS; off <<= 1) {
        unsigned int v = (tid + off < TOPK_THREADS) ? csum[tid + off] : 0u;
        __syncthreads();
        csum[tid] += v;
        __syncthreads();
    }

    // locate threshold bucket: cumAbove < K <= cumAbove + count
    unsigned int run = (tid < TOPK_THREADS - 1) ? csum[tid + 1] : 0u;
    for (int j = NBUCK / TOPK_THREADS - 1; j >= 0; --j) {
        unsigned int c = hist[base + j];
        if (run < (unsigned)K_ && run + c >= (unsigned)K_) bstar = base + j;  // unique writer
        run += c;
    }
    __syncthreads();
    int bs = bstar;

    // gather candidates; key = score_bits<<32 | (UINT_MAX - idx)
    for (int j = tid; j < QC / 4; j += TOPK_THREADS) {
        f32x4_t v4 = lg4[j];
#pragma unroll
        for (int c = 0; c < 4; ++c) {
            int i = j * 4 + c;
            float s = 1.0f / (1.0f + expf(-v4[c]));
            unsigned int bits = __float_as_uint(s);
            if ((int)(bits >> 19) >= bs) {
                unsigned int pos = atomicAdd(&candCount, 1u);
                if (pos < CAND)
                    cand[pos] = ((unsigned long long)bits << 32)
                              | (unsigned long long)(0xFFFFFFFFu - (unsigned int)i);
            }
        }
    }
    __syncthreads();
    unsigned int n = candCount; if (n > CAND) n = CAND;

    // rank-by-counting: LDS reads of cand[j] are lockstep -> broadcast, conflict-free.
    for (unsigned int i = tid; i < n; i += TOPK_THREADS) {
        unsigned long long ki = cand[i];
        unsigned int rank = 0;
        for (unsigned int j = 0; j < n; ++j)
            rank += (cand[j] > ki) ? 1u : 0u;
        if (rank < (unsigned)K_) sorted[rank] = ki;
    }
    __syncthreads();

    // emit
    float Sf = (float)S;
    float* out_labels = out;
    float* out_boxes  = out + (size_t)B * K_;
    float* out_scores = out + (size_t)B * K_ * 5;
    if (tid < K_) {
        unsigned long long key = sorted[tid];
        unsigned int bits = (unsigned int)(key >> 32);
        unsigned int idx  = 0xFFFFFFFFu - (unsigned int)(key & 0xFFFFFFFFull);
        int label = (int)(idx % C_);
        int q     = (int)(idx / C_);
        const float* bx = boxes_in + ((size_t)b * Q_ + q) * 4;
        float cx = bx[0], cy = bx[1], bw = bx[2], bh = bx[3];
        float x1 = (cx - bw * 0.5f) * Sf;
        float y1 = (cy - bh * 0.5f) * Sf;
        float x2 = (cx + bw * 0.5f) * Sf;
        float y2 = (cy + bh * 0.5f) * Sf;
        int o = b * K_ + tid;
        out_labels[o] = (float)label;
        out_scores[o] = __uint_as_float(bits);
        out_boxes[(size_t)o * 4 + 0] = x1;
        out_boxes[(size_t)o * 4 + 1] = y1;
        out_boxes[(size_t)o * 4 + 2] = x2;
        out_boxes[(size_t)o * 4 + 3] = y2;
        int xi1 = min(max((int)truncf(x1), 0), S);
        int yi1 = min(max((int)truncf(y1), 0), S);
        int xi2 = min(max((int)truncf(x2), 0), S);
        int yi2 = min(max((int)truncf(y2), 0), S);
        meta[(size_t)o * 5 + 0] = q;
        meta[(size_t)o * 5 + 1] = xi1;
        meta[(size_t)o * 5 + 2] = yi1;
        meta[(size_t)o * 5 + 3] = xi2;
        meta[(size_t)o * 5 + 4] = yi2;
    }
}

// -------- Kernel 2 (S=512): 64-row tiles; LDS-staged; XCD-chunked; NT stores; 8 blocks/CU --------
__global__ __launch_bounds__(256, 8) void mask_kernel_512(
    const float* __restrict__ masks,  // [B,Q,HM,WM]
    const int* __restrict__ meta,     // [B*K,5]
    float* __restrict__ out_masks,    // [B*K,512,512]
    int nwork)                        // B*K*8
{
    constexpr int S = 512;
    constexpr float ISC = 0.3125f;  // HM/S exact
    __shared__ float lds[22 * WM];  // up to 22 source rows (64 out rows * 0.3125 + 2)

    int bid = blockIdx.x;
    int chunk = nwork >> 3;                    // nwork % 8 == 0
    int work = (bid & 7) * chunk + (bid >> 3); // XCD-chunked, bijective
    int bk = work >> 3;
    int yt = work & 7;

    int b = bk / K_;
    const int* m = meta + (size_t)bk * 5;
    int q  = m[0];
    int x1 = m[1], y1 = m[2], x2 = m[3], y2 = m[4];
    const float* src = masks + ((size_t)b * Q_ + q) * (HM * WM);
    float* dst = out_masks + (size_t)bk * S * S;
    int yb0 = yt << 6;  // 64 rows per block

    // Block-level fast path: whole 64-row stripe is zero
    bool stripeLive = (y1 < yb0 + 64) && (y2 > yb0) && (y1 < y2) &&
                      (x1 < x2) && (x1 < S) && (x2 > 0);
    if (!stripeLive) {
        f32x4_t z = (f32x4_t)(0.0f);
        f32x4_t* base2 = reinterpret_cast<f32x4_t*>(dst + (size_t)yb0 * S);
        for (int t = threadIdx.x; t < 64 * 128; t += 256)
            __builtin_nontemporal_store(z, base2 + t);
        return;
    }

    // Stage the needed source rows into LDS (coalesced float4, once per block).
    int fFirst = (int)floorf((yb0 + 0.5f) * ISC - 0.5f);
    int fLast  = (int)floorf((yb0 + 63.5f) * ISC - 0.5f);
    int rowBase = max(fFirst, 0);
    int rowEnd  = min(fLast + 1, HM - 1);
    int nf4 = (rowEnd - rowBase + 1) * (WM / 4);
    {
        const f32x4_t* g4 = reinterpret_cast<const f32x4_t*>(src + (size_t)rowBase * WM);
        f32x4_t* l4 = reinterpret_cast<f32x4_t*>(lds);
        for (int i = threadIdx.x; i < nf4; i += 256) l4[i] = g4[i];
    }
    __syncthreads();

    // 64 rows x 128 float4-chunks; wave-uniform row test, per-lane x-window test
    for (int t = threadIdx.x; t < 64 * 128; t += 256) {
        int ry = t >> 7;
        int xq = t & 127;
        int y  = yb0 + ry;
        int x0 = xq << 2;
        f32x4_t r = (f32x4_t)(0.0f);
        if (y >= y1 && y < y2 && x0 + 4 > x1 && x0 < x2) {
            float iy  = (y + 0.5f) * ISC - 0.5f;
            float fyf = floorf(iy);
            int   y0i = (int)fyf;
            float fy  = iy - fyf;
            int ya = max(y0i, 0);
            int yb = min(y0i + 1, HM - 1);
            const float* r0 = lds + (size_t)(ya - rowBase) * WM;
            const float* r1 = lds + (size_t)(yb - rowBase) * WM;
            float wy0 = 1.0f - fy, wy1 = fy;

            // 3-wide input window shared by the 4 pixels
            float ib  = (x0 + 0.5f) * ISC - 0.5f;
            int   fb  = (int)floorf(ib);
            int i0 = max(fb, 0);
            int i1 = min(fb + 1, WM - 1);
            int i2 = min(fb + 2, WM - 1);
            float a0 = r0[i0], a1 = r0[i1], a2 = r0[i2];
            float b0 = r1[i0], b1 = r1[i1], b2 = r1[i2];

            float v[4];
#pragma unroll
            for (int c = 0; c < 4; ++c) {
                int x = x0 + c;
                float vv = 0.0f;
                if (x >= x1 && x < x2) {
                    float ix  = (x + 0.5f) * ISC - 0.5f;
                    float fxf = floorf(ix);
                    int   x0i = (int)fxf;
                    float fx  = ix - fxf;
                    int o = x0i - fb;           // 0 or 1
                    float va = o ? a1 : a0;
                    float vb = o ? a2 : a1;
                    float wa = o ? b1 : b0;
                    float wb = o ? b2 : b1;
                    float wx0 = 1.0f - fx, wx1 = fx;
                    float top = wx0 * va + wx1 * vb;
                    float bot = wx0 * wa + wx1 * wb;
                    float val = wy0 * top + wy1 * bot;
                    vv = (val > 0.0f) ? 1.0f : 0.0f;
                }
                v[c] = vv;
            }
            r = (f32x4_t){v[0], v[1], v[2], v[3]};
        }
        __builtin_nontemporal_store(r, reinterpret_cast<f32x4_t*>(dst + (size_t)y * S + x0));
    }
}

// -------- Generic fallback (round-1 validated path) --------
__global__ __launch_bounds__(256) void mask_kernel_generic(
    const float* __restrict__ masks,
    const int* __restrict__ meta,
    float* __restrict__ out_masks,
    int S, int rowsPerTile)
{
    int bk = blockIdx.x;
    int ytile = blockIdx.y;
    int b = bk / K_;
    const int* m = meta + (size_t)bk * 5;
    int q  = m[0];
    int x1 = m[1], y1 = m[2], x2 = m[3], y2 = m[4];
    const float* src = masks + ((size_t)b * Q_ + q) * (HM * WM);
    float* dst = out_masks + (size_t)bk * S * S;
    float inv_scale = (float)((double)HM / (double)S);

    int qx = S >> 2;
    int total = rowsPerTile * qx;
    for (int t = threadIdx.x; t < total; t += 256) {
        int ry = t / qx;
        int xq = t - ry * qx;
        int y  = ytile * rowsPerTile + ry;
        int x0 = xq << 2;
        float4 r = make_float4(0.0f, 0.0f, 0.0f, 0.0f);
        if (y >= y1 && y < y2) {
            float iy  = (y + 0.5f) * inv_scale - 0.5f;
            float fyf = floorf(iy);
            int   y0i = (int)fyf;
            float fy  = iy - fyf;
            int ya = max(y0i, 0);
            int yb = min(y0i + 1, HM - 1);
            const float* r0 = src + (size_t)ya * WM;
            const float* r1 = src + (size_t)yb * WM;
            float wy0 = 1.0f - fy, wy1 = fy;
            float v[4];
#pragma unroll
            for (int c = 0; c < 4; ++c) {
                int x = x0 + c;
                float vv = 0.0f;
                if (x >= x1 && x < x2) {
                    float ix  = (x + 0.5f) * inv_scale - 0.5f;
                    float fxf = floorf(ix);
                    int   x0i = (int)fxf;
                    float fx  = ix - fxf;
                    int xa = max(x0i, 0);
                    int xb = min(x0i + 1, WM - 1);
                    float wx0 = 1.0f - fx, wx1 = fx;
                    float top = wx0 * r0[xa] + wx1 * r0[xb];
                    float bot = wx0 * r1[xa] + wx1 * r1[xb];
                    float val = wy0 * top + wy1 * bot;
                    vv = (val > 0.0f) ? 1.0f : 0.0f;
                }
                v[c] = vv;
            }
            r = make_float4(v[0], v[1], v[2], v[3]);
        }
        *reinterpret_cast<float4*>(dst + (size_t)y * S + x0) = r;
    }
}

extern "C" void kernel_launch(void* const* d_in, const int* in_sizes, int n_in,
                              void* d_out, int out_size, void* d_ws, size_t ws_size,
                              hipStream_t stream) {
    const float* pred_logits = (const float*)d_in[0];
    const float* pred_boxes  = (const float*)d_in[1];
    const float* pred_masks  = (const float*)d_in[2];

    int B = in_sizes[0] / QC;
    long long mask_elems = (long long)out_size - (long long)B * K_ * 6;
    int S = (int)llroundf(sqrtf((float)(mask_elems / ((long long)B * K_))));
    if (S <= 0) S = 512;

    float* out = (float*)d_out;
    int* meta = (int*)d_ws;

    topk_kernel<<<dim3(B), dim3(TOPK_THREADS), 0, stream>>>(
        pred_logits, pred_boxes, out, meta, B, S);

    float* out_masks = out + (size_t)B * K_ * 6;
    if (S == 512) {
        int nwork = B * K_ * 8;  // 64-row tiles; divisible by 8
        mask_kernel_512<<<dim3(nwork), dim3(256), 0, stream>>>(
            pred_masks, meta, out_masks, nwork);
    } else {
        int rowsPerTile = 32;
        int ntile = (S + rowsPerTile - 1) / rowsPerTile;
        mask_kernel_generic<<<dim3(B * K_, ntile), dim3(256), 0, stream>>>(
            pred_masks, meta, out_masks, S, rowsPerTile);
    }
}

// Round 13
// 266.031 us; speedup vs baseline: 1.1394x; 1.1065x over previous
//
#include <hip/hip_runtime.h>
#include <cstdint>
#include <cmath>

#define Q_ 300
#define C_ 80
#define QC (Q_ * C_)
#define K_ 300
#define HM 160
#define WM 160
#define NBUCK 8192
#define CAND 2048
#define TOPK_THREADS 512

typedef float f32x4_t __attribute__((ext_vector_type(4)));

// -------- Kernel 1: per-batch top-K over sigmoid(logits) --------
// (round-10 validated: histogram-select + rank-by-counting, vectorized loads)
__global__ __launch_bounds__(TOPK_THREADS) void topk_kernel(
    const float* __restrict__ logits,   // [B,Q,C]
    const float* __restrict__ boxes_in, // [B,Q,4] cxcywh
    float* __restrict__ out,            // labels[B,K] | boxes[B,K,4] | scores[B,K]
    int* __restrict__ meta,             // [B*K,5] : q, x1,y1,x2,y2
    int B, int S)
{
    int b = blockIdx.x;
    int tid = threadIdx.x;
    __shared__ unsigned int hist[NBUCK];
    __shared__ unsigned int csum[TOPK_THREADS];
    __shared__ unsigned long long cand[CAND];
    __shared__ unsigned long long sorted[K_];
    __shared__ unsigned int candCount;
    __shared__ int bstar;

    for (int i = tid; i < NBUCK; i += TOPK_THREADS) hist[i] = 0u;
    if (tid == 0) { candCount = 0u; bstar = 0; }
    __syncthreads();

    const float* lg = logits + (size_t)b * QC;
    const f32x4_t* lg4 = reinterpret_cast<const f32x4_t*>(lg);

    // histogram over top 13 bits of score bit pattern (monotone for positive floats)
    for (int j = tid; j < QC / 4; j += TOPK_THREADS) {
        f32x4_t v4 = lg4[j];
#pragma unroll
        for (int c = 0; c < 4; ++c) {
            float s = 1.0f / (1.0f + expf(-v4[c]));
            unsigned int bits = __float_as_uint(s);
            atomicAdd(&hist[bits >> 19], 1u);
        }
    }
    __syncthreads();

    // per-thread chunk of 16 buckets -> chunk sum
    unsigned int chunkSum = 0u;
    int base = tid * (NBUCK / TOPK_THREADS);
#pragma unroll
    for (int j = 0; j < NBUCK / TOPK_THREADS; ++j) chunkSum += hist[base + j];
    csum[tid] = chunkSum;
    __syncthreads();

    // suffix-inclusive scan: csum[t] = sum_{t'>=t}
    for (int off = 1; off < TOPK_THREADS; off <<= 1) {
        unsigned int v = (tid + off < TOPK_THREADS) ? csum[tid + off] : 0u;
        __syncthreads();
        csum[tid] += v;
        __syncthreads();
    }

    // locate threshold bucket: cumAbove < K <= cumAbove + count
    unsigned int run = (tid < TOPK_THREADS - 1) ? csum[tid + 1] : 0u;
    for (int j = NBUCK / TOPK_THREADS - 1; j >= 0; --j) {
        unsigned int c = hist[base + j];
        if (run < (unsigned)K_ && run + c >= (unsigned)K_) bstar = base + j;  // unique writer
        run += c;
    }
    __syncthreads();
    int bs = bstar;

    // gather candidates; key = score_bits<<32 | (UINT_MAX - idx)
    for (int j = tid; j < QC / 4; j += TOPK_THREADS) {
        f32x4_t v4 = lg4[j];
#pragma unroll
        for (int c = 0; c < 4; ++c) {
            int i = j * 4 + c;
            float s = 1.0f / (1.0f + expf(-v4[c]));
            unsigned int bits = __float_as_uint(s);
            if ((int)(bits >> 19) >= bs) {
                unsigned int pos = atomicAdd(&candCount, 1u);
                if (pos < CAND)
                    cand[pos] = ((unsigned long long)bits << 32)
                              | (unsigned long long)(0xFFFFFFFFu - (unsigned int)i);
            }
        }
    }
    __syncthreads();
    unsigned int n = candCount; if (n > CAND) n = CAND;

    // rank-by-counting: LDS reads of cand[j] are lockstep -> broadcast, conflict-free.
    for (unsigned int i = tid; i < n; i += TOPK_THREADS) {
        unsigned long long ki = cand[i];
        unsigned int rank = 0;
        for (unsigned int j = 0; j < n; ++j)
            rank += (cand[j] > ki) ? 1u : 0u;
        if (rank < (unsigned)K_) sorted[rank] = ki;
    }
    __syncthreads();

    // emit
    float Sf = (float)S;
    float* out_labels = out;
    float* out_boxes  = out + (size_t)B * K_;
    float* out_scores = out + (size_t)B * K_ * 5;
    if (tid < K_) {
        unsigned long long key = sorted[tid];
        unsigned int bits = (unsigned int)(key >> 32);
        unsigned int idx  = 0xFFFFFFFFu - (unsigned int)(key & 0xFFFFFFFFull);
        int label = (int)(idx % C_);
        int q     = (int)(idx / C_);
        const float* bx = boxes_in + ((size_t)b * Q_ + q) * 4;
        float cx = bx[0], cy = bx[1], bw = bx[2], bh = bx[3];
        float x1 = (cx - bw * 0.5f) * Sf;
        float y1 = (cy - bh * 0.5f) * Sf;
        float x2 = (cx + bw * 0.5f) * Sf;
        float y2 = (cy + bh * 0.5f) * Sf;
        int o = b * K_ + tid;
        out_labels[o] = (float)label;
        out_scores[o] = __uint_as_float(bits);
        out_boxes[(size_t)o * 4 + 0] = x1;
        out_boxes[(size_t)o * 4 + 1] = y1;
        out_boxes[(size_t)o * 4 + 2] = x2;
        out_boxes[(size_t)o * 4 + 3] = y2;
        int xi1 = min(max((int)truncf(x1), 0), S);
        int yi1 = min(max((int)truncf(y1), 0), S);
        int xi2 = min(max((int)truncf(x2), 0), S);
        int yi2 = min(max((int)truncf(y2), 0), S);
        meta[(size_t)o * 5 + 0] = q;
        meta[(size_t)o * 5 + 1] = xi1;
        meta[(size_t)o * 5 + 2] = yi1;
        meta[(size_t)o * 5 + 3] = xi2;
        meta[(size_t)o * 5 + 4] = yi2;
    }
}

// -------- Kernel 2 (S=512): 16-row tiles; LDS-staged; XCD-chunked; NT stores; 8 blocks/CU --------
__global__ __launch_bounds__(256, 8) void mask_kernel_512(
    const float* __restrict__ masks,  // [B,Q,HM,WM]
    const int* __restrict__ meta,     // [B*K,5]
    float* __restrict__ out_masks,    // [B*K,512,512]
    int nwork)                        // B*K*32
{
    constexpr int S = 512;
    constexpr float ISC = 0.3125f;  // HM/S exact
    __shared__ float lds[7 * WM];   // up to 7 source rows (16*0.3125 + 2)

    int bid = blockIdx.x;
    int chunk = nwork >> 3;                    // nwork % 8 == 0
    int work = (bid & 7) * chunk + (bid >> 3); // XCD-chunked, bijective
    int bk = work >> 5;
    int yt = work & 31;

    int b = bk / K_;
    const int* m = meta + (size_t)bk * 5;
    int q  = m[0];
    int x1 = m[1], y1 = m[2], x2 = m[3], y2 = m[4];
    const float* src = masks + ((size_t)b * Q_ + q) * (HM * WM);
    float* dst = out_masks + (size_t)bk * S * S;
    int yb0 = yt << 4;  // 16 rows per block

    // Block-level fast path: whole 16-row stripe is zero
    bool stripeLive = (y1 < yb0 + 16) && (y2 > yb0) && (y1 < y2) &&
                      (x1 < x2) && (x1 < S) && (x2 > 0);
    if (!stripeLive) {
        f32x4_t z = (f32x4_t)(0.0f);
        f32x4_t* base2 = reinterpret_cast<f32x4_t*>(dst + (size_t)yb0 * S);
        for (int t = threadIdx.x; t < 16 * 128; t += 256)
            __builtin_nontemporal_store(z, base2 + t);
        return;
    }

    // Stage the needed source rows into LDS (coalesced float4, once per block).
    int fFirst = (int)floorf((yb0 + 0.5f) * ISC - 0.5f);
    int fLast  = (int)floorf((yb0 + 15.5f) * ISC - 0.5f);
    int rowBase = max(fFirst, 0);
    int rowEnd  = min(fLast + 1, HM - 1);
    int nf4 = (rowEnd - rowBase + 1) * (WM / 4);
    {
        const f32x4_t* g4 = reinterpret_cast<const f32x4_t*>(src + (size_t)rowBase * WM);
        f32x4_t* l4 = reinterpret_cast<f32x4_t*>(lds);
        for (int i = threadIdx.x; i < nf4; i += 256) l4[i] = g4[i];
    }
    __syncthreads();

    // 16 rows x 128 float4-chunks; wave-uniform row test, per-lane x-window test
    for (int t = threadIdx.x; t < 16 * 128; t += 256) {
        int ry = t >> 7;
        int xq = t & 127;
        int y  = yb0 + ry;
        int x0 = xq << 2;
        f32x4_t r = (f32x4_t)(0.0f);
        if (y >= y1 && y < y2 && x0 + 4 > x1 && x0 < x2) {
            float iy  = (y + 0.5f) * ISC - 0.5f;
            float fyf = floorf(iy);
            int   y0i = (int)fyf;
            float fy  = iy - fyf;
            int ya = max(y0i, 0);
            int yb = min(y0i + 1, HM - 1);
            const float* r0 = lds + (size_t)(ya - rowBase) * WM;
            const float* r1 = lds + (size_t)(yb - rowBase) * WM;
            float wy0 = 1.0f - fy, wy1 = fy;

            // 3-wide input window shared by the 4 pixels
            float ib  = (x0 + 0.5f) * ISC - 0.5f;
            int   fb  = (int)floorf(ib);
            int i0 = max(fb, 0);
            int i1 = min(fb + 1, WM - 1);
            int i2 = min(fb + 2, WM - 1);
            float a0 = r0[i0], a1 = r0[i1], a2 = r0[i2];
            float b0 = r1[i0], b1 = r1[i1], b2 = r1[i2];

            float v[4];
#pragma unroll
            for (int c = 0; c < 4; ++c) {
                int x = x0 + c;
                float vv = 0.0f;
                if (x >= x1 && x < x2) {
                    float ix  = (x + 0.5f) * ISC - 0.5f;
                    float fxf = floorf(ix);
                    int   x0i = (int)fxf;
                    float fx  = ix - fxf;
                    int o = x0i - fb;           // 0 or 1
                    float va = o ? a1 : a0;
                    float vb = o ? a2 : a1;
                    float wa = o ? b1 : b0;
                    float wb = o ? b2 : b1;
                    float wx0 = 1.0f - fx, wx1 = fx;
                    float top = wx0 * va + wx1 * vb;
                    float bot = wx0 * wa + wx1 * wb;
                    float val = wy0 * top + wy1 * bot;
                    vv = (val > 0.0f) ? 1.0f : 0.0f;
                }
                v[c] = vv;
            }
            r = (f32x4_t){v[0], v[1], v[2], v[3]};
        }
        __builtin_nontemporal_store(r, reinterpret_cast<f32x4_t*>(dst + (size_t)y * S + x0));
    }
}

// -------- Generic fallback (round-1 validated path) --------
__global__ __launch_bounds__(256) void mask_kernel_generic(
    const float* __restrict__ masks,
    const int* __restrict__ meta,
    float* __restrict__ out_masks,
    int S, int rowsPerTile)
{
    int bk = blockIdx.x;
    int ytile = blockIdx.y;
    int b = bk / K_;
    const int* m = meta + (size_t)bk * 5;
    int q  = m[0];
    int x1 = m[1], y1 = m[2], x2 = m[3], y2 = m[4];
    const float* src = masks + ((size_t)b * Q_ + q) * (HM * WM);
    float* dst = out_masks + (size_t)bk * S * S;
    float inv_scale = (float)((double)HM / (double)S);

    int qx = S >> 2;
    int total = rowsPerTile * qx;
    for (int t = threadIdx.x; t < total; t += 256) {
        int ry = t / qx;
        int xq = t - ry * qx;
        int y  = ytile * rowsPerTile + ry;
        int x0 = xq << 2;
        float4 r = make_float4(0.0f, 0.0f, 0.0f, 0.0f);
        if (y >= y1 && y < y2) {
            float iy  = (y + 0.5f) * inv_scale - 0.5f;
            float fyf = floorf(iy);
            int   y0i = (int)fyf;
            float fy  = iy - fyf;
            int ya = max(y0i, 0);
            int yb = min(y0i + 1, HM - 1);
            const float* r0 = src + (size_t)ya * WM;
            const float* r1 = src + (size_t)yb * WM;
            float wy0 = 1.0f - fy, wy1 = fy;
            float v[4];
#pragma unroll
            for (int c = 0; c < 4; ++c) {
                int x = x0 + c;
                float vv = 0.0f;
                if (x >= x1 && x < x2) {
                    float ix  = (x + 0.5f) * inv_scale - 0.5f;
                    float fxf = floorf(ix);
                    int   x0i = (int)fxf;
                    float fx  = ix - fxf;
                    int xa = max(x0i, 0);
                    int xb = min(x0i + 1, WM - 1);
                    float wx0 = 1.0f - fx, wx1 = fx;
                    float top = wx0 * r0[xa] + wx1 * r0[xb];
                    float bot = wx0 * r1[xa] + wx1 * r1[xb];
                    float val = wy0 * top + wy1 * bot;
                    vv = (val > 0.0f) ? 1.0f : 0.0f;
                }
                v[c] = vv;
            }
            r = make_float4(v[0], v[1], v[2], v[3]);
        }
        *reinterpret_cast<float4*>(dst + (size_t)y * S + x0) = r;
    }
}

extern "C" void kernel_launch(void* const* d_in, const int* in_sizes, int n_in,
                              void* d_out, int out_size, void* d_ws, size_t ws_size,
                              hipStream_t stream) {
    const float* pred_logits = (const float*)d_in[0];
    const float* pred_boxes  = (const float*)d_in[1];
    const float* pred_masks  = (const float*)d_in[2];

    int B = in_sizes[0] / QC;
    long long mask_elems = (long long)out_size - (long long)B * K_ * 6;
    int S = (int)llroundf(sqrtf((float)(mask_elems / ((long long)B * K_))));
    if (S <= 0) S = 512;

    float* out = (float*)d_out;
    int* meta = (int*)d_ws;

    topk_kernel<<<dim3(B), dim3(TOPK_THREADS), 0, stream>>>(
        pred_logits, pred_boxes, out, meta, B, S);

    float* out_masks = out + (size_t)B * K_ * 6;
    if (S == 512) {
        int nwork = B * K_ * 32;  // 16-row tiles; divisible by 8
        mask_kernel_512<<<dim3(nwork), dim3(256), 0, stream>>>(
            pred_masks, meta, out_masks, nwork);
    } else {
        int rowsPerTile = 32;
        int ntile = (S + rowsPerTile - 1) / rowsPerTile;
        mask_kernel_generic<<<dim3(B * K_, ntile), dim3(256), 0, stream>>>(
            pred_masks, meta, out_masks, S, rowsPerTile);
    }
}

// Round 14
// 256.085 us; speedup vs baseline: 1.1836x; 1.0388x over previous
//
#include <hip/hip_runtime.h>
#include <cstdint>
#include <cmath>

#define Q_ 300
#define C_ 80
#define QC (Q_ * C_)
#define K_ 300
#define HM 160
#define WM 160
#define NBUCK 8192
#define CAND 2048
#define TOPK_THREADS 512

typedef float f32x4_t __attribute__((ext_vector_type(4)));

// -------- Kernel 1: per-batch top-K over sigmoid(logits) --------
// (round-10 validated: histogram-select + rank-by-counting, vectorized loads)
__global__ __launch_bounds__(TOPK_THREADS) void topk_kernel(
    const float* __restrict__ logits,   // [B,Q,C]
    const float* __restrict__ boxes_in, // [B,Q,4] cxcywh
    float* __restrict__ out,            // labels[B,K] | boxes[B,K,4] | scores[B,K]
    int* __restrict__ meta,             // [B*K,5] : q, x1,y1,x2,y2
    int B, int S)
{
    int b = blockIdx.x;
    int tid = threadIdx.x;
    __shared__ unsigned int hist[NBUCK];
    __shared__ unsigned int csum[TOPK_THREADS];
    __shared__ unsigned long long cand[CAND];
    __shared__ unsigned long long sorted[K_];
    __shared__ unsigned int candCount;
    __shared__ int bstar;

    for (int i = tid; i < NBUCK; i += TOPK_THREADS) hist[i] = 0u;
    if (tid == 0) { candCount = 0u; bstar = 0; }
    __syncthreads();

    const float* lg = logits + (size_t)b * QC;
    const f32x4_t* lg4 = reinterpret_cast<const f32x4_t*>(lg);

    // histogram over top 13 bits of score bit pattern (monotone for positive floats)
    for (int j = tid; j < QC / 4; j += TOPK_THREADS) {
        f32x4_t v4 = lg4[j];
#pragma unroll
        for (int c = 0; c < 4; ++c) {
            float s = 1.0f / (1.0f + expf(-v4[c]));
            unsigned int bits = __float_as_uint(s);
            atomicAdd(&hist[bits >> 19], 1u);
        }
    }
    __syncthreads();

    // per-thread chunk of 16 buckets -> chunk sum
    unsigned int chunkSum = 0u;
    int base = tid * (NBUCK / TOPK_THREADS);
#pragma unroll
    for (int j = 0; j < NBUCK / TOPK_THREADS; ++j) chunkSum += hist[base + j];
    csum[tid] = chunkSum;
    __syncthreads();

    // suffix-inclusive scan: csum[t] = sum_{t'>=t}
    for (int off = 1; off < TOPK_THREADS; off <<= 1) {
        unsigned int v = (tid + off < TOPK_THREADS) ? csum[tid + off] : 0u;
        __syncthreads();
        csum[tid] += v;
        __syncthreads();
    }

    // locate threshold bucket: cumAbove < K <= cumAbove + count
    unsigned int run = (tid < TOPK_THREADS - 1) ? csum[tid + 1] : 0u;
    for (int j = NBUCK / TOPK_THREADS - 1; j >= 0; --j) {
        unsigned int c = hist[base + j];
        if (run < (unsigned)K_ && run + c >= (unsigned)K_) bstar = base + j;  // unique writer
        run += c;
    }
    __syncthreads();
    int bs = bstar;

    // gather candidates; key = score_bits<<32 | (UINT_MAX - idx)
    for (int j = tid; j < QC / 4; j += TOPK_THREADS) {
        f32x4_t v4 = lg4[j];
#pragma unroll
        for (int c = 0; c < 4; ++c) {
            int i = j * 4 + c;
            float s = 1.0f / (1.0f + expf(-v4[c]));
            unsigned int bits = __float_as_uint(s);
            if ((int)(bits >> 19) >= bs) {
                unsigned int pos = atomicAdd(&candCount, 1u);
                if (pos < CAND)
                    cand[pos] = ((unsigned long long)bits << 32)
                              | (unsigned long long)(0xFFFFFFFFu - (unsigned int)i);
            }
        }
    }
    __syncthreads();
    unsigned int n = candCount; if (n > CAND) n = CAND;

    // rank-by-counting: LDS reads of cand[j] are lockstep -> broadcast, conflict-free.
    for (unsigned int i = tid; i < n; i += TOPK_THREADS) {
        unsigned long long ki = cand[i];
        unsigned int rank = 0;
        for (unsigned int j = 0; j < n; ++j)
            rank += (cand[j] > ki) ? 1u : 0u;
        if (rank < (unsigned)K_) sorted[rank] = ki;
    }
    __syncthreads();

    // emit
    float Sf = (float)S;
    float* out_labels = out;
    float* out_boxes  = out + (size_t)B * K_;
    float* out_scores = out + (size_t)B * K_ * 5;
    if (tid < K_) {
        unsigned long long key = sorted[tid];
        unsigned int bits = (unsigned int)(key >> 32);
        unsigned int idx  = 0xFFFFFFFFu - (unsigned int)(key & 0xFFFFFFFFull);
        int label = (int)(idx % C_);
        int q     = (int)(idx / C_);
        const float* bx = boxes_in + ((size_t)b * Q_ + q) * 4;
        float cx = bx[0], cy = bx[1], bw = bx[2], bh = bx[3];
        float x1 = (cx - bw * 0.5f) * Sf;
        float y1 = (cy - bh * 0.5f) * Sf;
        float x2 = (cx + bw * 0.5f) * Sf;
        float y2 = (cy + bh * 0.5f) * Sf;
        int o = b * K_ + tid;
        out_labels[o] = (float)label;
        out_scores[o] = __uint_as_float(bits);
        out_boxes[(size_t)o * 4 + 0] = x1;
        out_boxes[(size_t)o * 4 + 1] = y1;
        out_boxes[(size_t)o * 4 + 2] = x2;
        out_boxes[(size_t)o * 4 + 3] = y2;
        int xi1 = min(max((int)truncf(x1), 0), S);
        int yi1 = min(max((int)truncf(y1), 0), S);
        int xi2 = min(max((int)truncf(x2), 0), S);
        int yi2 = min(max((int)truncf(y2), 0), S);
        meta[(size_t)o * 5 + 0] = q;
        meta[(size_t)o * 5 + 1] = xi1;
        meta[(size_t)o * 5 + 2] = yi1;
        meta[(size_t)o * 5 + 3] = xi2;
        meta[(size_t)o * 5 + 4] = yi2;
    }
}

// -------- Kernel 2 (S=512): 8-row tiles; LDS-staged; XCD-chunked; NT stores; 8 blocks/CU --------
__global__ __launch_bounds__(256, 8) void mask_kernel_512(
    const float* __restrict__ masks,  // [B,Q,HM,WM]
    const int* __restrict__ meta,     // [B*K,5]
    float* __restrict__ out_masks,    // [B*K,512,512]
    int nwork)                        // B*K*64
{
    constexpr int S = 512;
    constexpr float ISC = 0.3125f;  // HM/S exact
    __shared__ float lds[5 * WM];   // up to 5 source rows (8*0.3125 + 2)

    int bid = blockIdx.x;
    int chunk = nwork >> 3;                    // nwork % 8 == 0
    int work = (bid & 7) * chunk + (bid >> 3); // XCD-chunked, bijective
    int bk = work >> 6;
    int yt = work & 63;

    int b = bk / K_;
    const int* m = meta + (size_t)bk * 5;
    int q  = m[0];
    int x1 = m[1], y1 = m[2], x2 = m[3], y2 = m[4];
    const float* src = masks + ((size_t)b * Q_ + q) * (HM * WM);
    float* dst = out_masks + (size_t)bk * S * S;
    int yb0 = yt << 3;  // 8 rows per block

    // Block-level fast path: whole 8-row stripe is zero
    bool stripeLive = (y1 < yb0 + 8) && (y2 > yb0) && (y1 < y2) &&
                      (x1 < x2) && (x1 < S) && (x2 > 0);
    if (!stripeLive) {
        f32x4_t z = (f32x4_t)(0.0f);
        f32x4_t* base2 = reinterpret_cast<f32x4_t*>(dst + (size_t)yb0 * S);
        for (int t = threadIdx.x; t < 8 * 128; t += 256)
            __builtin_nontemporal_store(z, base2 + t);
        return;
    }

    // Stage the needed source rows into LDS (coalesced float4, once per block).
    int fFirst = (int)floorf((yb0 + 0.5f) * ISC - 0.5f);
    int fLast  = (int)floorf((yb0 + 7.5f) * ISC - 0.5f);
    int rowBase = max(fFirst, 0);
    int rowEnd  = min(fLast + 1, HM - 1);
    int nf4 = (rowEnd - rowBase + 1) * (WM / 4);
    {
        const f32x4_t* g4 = reinterpret_cast<const f32x4_t*>(src + (size_t)rowBase * WM);
        f32x4_t* l4 = reinterpret_cast<f32x4_t*>(lds);
        for (int i = threadIdx.x; i < nf4; i += 256) l4[i] = g4[i];
    }
    __syncthreads();

    // 8 rows x 128 float4-chunks; wave-uniform row test, per-lane x-window test
    for (int t = threadIdx.x; t < 8 * 128; t += 256) {
        int ry = t >> 7;
        int xq = t & 127;
        int y  = yb0 + ry;
        int x0 = xq << 2;
        f32x4_t r = (f32x4_t)(0.0f);
        if (y >= y1 && y < y2 && x0 + 4 > x1 && x0 < x2) {
            float iy  = (y + 0.5f) * ISC - 0.5f;
            float fyf = floorf(iy);
            int   y0i = (int)fyf;
            float fy  = iy - fyf;
            int ya = max(y0i, 0);
            int yb = min(y0i + 1, HM - 1);
            const float* r0 = lds + (size_t)(ya - rowBase) * WM;
            const float* r1 = lds + (size_t)(yb - rowBase) * WM;
            float wy0 = 1.0f - fy, wy1 = fy;

            // 3-wide input window shared by the 4 pixels
            float ib  = (x0 + 0.5f) * ISC - 0.5f;
            int   fb  = (int)floorf(ib);
            int i0 = max(fb, 0);
            int i1 = min(fb + 1, WM - 1);
            int i2 = min(fb + 2, WM - 1);
            float a0 = r0[i0], a1 = r0[i1], a2 = r0[i2];
            float b0 = r1[i0], b1 = r1[i1], b2 = r1[i2];

            float v[4];
#pragma unroll
            for (int c = 0; c < 4; ++c) {
                int x = x0 + c;
                float vv = 0.0f;
                if (x >= x1 && x < x2) {
                    float ix  = (x + 0.5f) * ISC - 0.5f;
                    float fxf = floorf(ix);
                    int   x0i = (int)fxf;
                    float fx  = ix - fxf;
                    int o = x0i - fb;           // 0 or 1
                    float va = o ? a1 : a0;
                    float vb = o ? a2 : a1;
                    float wa = o ? b1 : b0;
                    float wb = o ? b2 : b1;
                    float wx0 = 1.0f - fx, wx1 = fx;
                    float top = wx0 * va + wx1 * vb;
                    float bot = wx0 * wa + wx1 * wb;
                    float val = wy0 * top + wy1 * bot;
                    vv = (val > 0.0f) ? 1.0f : 0.0f;
                }
                v[c] = vv;
            }
            r = (f32x4_t){v[0], v[1], v[2], v[3]};
        }
        __builtin_nontemporal_store(r, reinterpret_cast<f32x4_t*>(dst + (size_t)y * S + x0));
    }
}

// -------- Generic fallback (round-1 validated path) --------
__global__ __launch_bounds__(256) void mask_kernel_generic(
    const float* __restrict__ masks,
    const int* __restrict__ meta,
    float* __restrict__ out_masks,
    int S, int rowsPerTile)
{
    int bk = blockIdx.x;
    int ytile = blockIdx.y;
    int b = bk / K_;
    const int* m = meta + (size_t)bk * 5;
    int q  = m[0];
    int x1 = m[1], y1 = m[2], x2 = m[3], y2 = m[4];
    const float* src = masks + ((size_t)b * Q_ + q) * (HM * WM);
    float* dst = out_masks + (size_t)bk * S * S;
    float inv_scale = (float)((double)HM / (double)S);

    int qx = S >> 2;
    int total = rowsPerTile * qx;
    for (int t = threadIdx.x; t < total; t += 256) {
        int ry = t / qx;
        int xq = t - ry * qx;
        int y  = ytile * rowsPerTile + ry;
        int x0 = xq << 2;
        float4 r = make_float4(0.0f, 0.0f, 0.0f, 0.0f);
        if (y >= y1 && y < y2) {
            float iy  = (y + 0.5f) * inv_scale - 0.5f;
            float fyf = floorf(iy);
            int   y0i = (int)fyf;
            float fy  = iy - fyf;
            int ya = max(y0i, 0);
            int yb = min(y0i + 1, HM - 1);
            const float* r0 = src + (size_t)ya * WM;
            const float* r1 = src + (size_t)yb * WM;
            float wy0 = 1.0f - fy, wy1 = fy;
            float v[4];
#pragma unroll
            for (int c = 0; c < 4; ++c) {
                int x = x0 + c;
                float vv = 0.0f;
                if (x >= x1 && x < x2) {
                    float ix  = (x + 0.5f) * inv_scale - 0.5f;
                    float fxf = floorf(ix);
                    int   x0i = (int)fxf;
                    float fx  = ix - fxf;
                    int xa = max(x0i, 0);
                    int xb = min(x0i + 1, WM - 1);
                    float wx0 = 1.0f - fx, wx1 = fx;
                    float top = wx0 * r0[xa] + wx1 * r0[xb];
                    float bot = wx0 * r1[xa] + wx1 * r1[xb];
                    float val = wy0 * top + wy1 * bot;
                    vv = (val > 0.0f) ? 1.0f : 0.0f;
                }
                v[c] = vv;
            }
            r = make_float4(v[0], v[1], v[2], v[3]);
        }
        *reinterpret_cast<float4*>(dst + (size_t)y * S + x0) = r;
    }
}

extern "C" void kernel_launch(void* const* d_in, const int* in_sizes, int n_in,
                              void* d_out, int out_size, void* d_ws, size_t ws_size,
                              hipStream_t stream) {
    const float* pred_logits = (const float*)d_in[0];
    const float* pred_boxes  = (const float*)d_in[1];
    const float* pred_masks  = (const float*)d_in[2];

    int B = in_sizes[0] / QC;
    long long mask_elems = (long long)out_size - (long long)B * K_ * 6;
    int S = (int)llroundf(sqrtf((float)(mask_elems / ((long long)B * K_))));
    if (S <= 0) S = 512;

    float* out = (float*)d_out;
    int* meta = (int*)d_ws;

    topk_kernel<<<dim3(B), dim3(TOPK_THREADS), 0, stream>>>(
        pred_logits, pred_boxes, out, meta, B, S);

    float* out_masks = out + (size_t)B * K_ * 6;
    if (S == 512) {
        int nwork = B * K_ * 64;  // 8-row tiles; divisible by 8
        mask_kernel_512<<<dim3(nwork), dim3(256), 0, stream>>>(
            pred_masks, meta, out_masks, nwork);
    } else {
        int rowsPerTile = 32;
        int ntile = (S + rowsPerTile - 1) / rowsPerTile;
        mask_kernel_generic<<<dim3(B * K_, ntile), dim3(256), 0, stream>>>(
            pred_masks, meta, out_masks, S, rowsPerTile);
    }
}

// Round 15
// 250.187 us; speedup vs baseline: 1.2115x; 1.0236x over previous
//
#include <hip/hip_runtime.h>
#include <cstdint>
#include <cmath>

#define Q_ 300
#define C_ 80
#define QC (Q_ * C_)
#define K_ 300
#define HM 160
#define WM 160
#define NBUCK 8192
#define CAND 2048
#define TOPK_THREADS 512

typedef float f32x4_t __attribute__((ext_vector_type(4)));

// -------- Kernel 1: per-batch top-K over sigmoid(logits) --------
// (round-10 validated: histogram-select + rank-by-counting, vectorized loads)
__global__ __launch_bounds__(TOPK_THREADS) void topk_kernel(
    const float* __restrict__ logits,   // [B,Q,C]
    const float* __restrict__ boxes_in, // [B,Q,4] cxcywh
    float* __restrict__ out,            // labels[B,K] | boxes[B,K,4] | scores[B,K]
    int* __restrict__ meta,             // [B*K,5] : q, x1,y1,x2,y2
    int B, int S)
{
    int b = blockIdx.x;
    int tid = threadIdx.x;
    __shared__ unsigned int hist[NBUCK];
    __shared__ unsigned int csum[TOPK_THREADS];
    __shared__ unsigned long long cand[CAND];
    __shared__ unsigned long long sorted[K_];
    __shared__ unsigned int candCount;
    __shared__ int bstar;

    for (int i = tid; i < NBUCK; i += TOPK_THREADS) hist[i] = 0u;
    if (tid == 0) { candCount = 0u; bstar = 0; }
    __syncthreads();

    const float* lg = logits + (size_t)b * QC;
    const f32x4_t* lg4 = reinterpret_cast<const f32x4_t*>(lg);

    // histogram over top 13 bits of score bit pattern (monotone for positive floats)
    for (int j = tid; j < QC / 4; j += TOPK_THREADS) {
        f32x4_t v4 = lg4[j];
#pragma unroll
        for (int c = 0; c < 4; ++c) {
            float s = 1.0f / (1.0f + expf(-v4[c]));
            unsigned int bits = __float_as_uint(s);
            atomicAdd(&hist[bits >> 19], 1u);
        }
    }
    __syncthreads();

    // per-thread chunk of 16 buckets -> chunk sum
    unsigned int chunkSum = 0u;
    int base = tid * (NBUCK / TOPK_THREADS);
#pragma unroll
    for (int j = 0; j < NBUCK / TOPK_THREADS; ++j) chunkSum += hist[base + j];
    csum[tid] = chunkSum;
    __syncthreads();

    // suffix-inclusive scan: csum[t] = sum_{t'>=t}
    for (int off = 1; off < TOPK_THREADS; off <<= 1) {
        unsigned int v = (tid + off < TOPK_THREADS) ? csum[tid + off] : 0u;
        __syncthreads();
        csum[tid] += v;
        __syncthreads();
    }

    // locate threshold bucket: cumAbove < K <= cumAbove + count
    unsigned int run = (tid < TOPK_THREADS - 1) ? csum[tid + 1] : 0u;
    for (int j = NBUCK / TOPK_THREADS - 1; j >= 0; --j) {
        unsigned int c = hist[base + j];
        if (run < (unsigned)K_ && run + c >= (unsigned)K_) bstar = base + j;  // unique writer
        run += c;
    }
    __syncthreads();
    int bs = bstar;

    // gather candidates; key = score_bits<<32 | (UINT_MAX - idx)
    for (int j = tid; j < QC / 4; j += TOPK_THREADS) {
        f32x4_t v4 = lg4[j];
#pragma unroll
        for (int c = 0; c < 4; ++c) {
            int i = j * 4 + c;
            float s = 1.0f / (1.0f + expf(-v4[c]));
            unsigned int bits = __float_as_uint(s);
            if ((int)(bits >> 19) >= bs) {
                unsigned int pos = atomicAdd(&candCount, 1u);
                if (pos < CAND)
                    cand[pos] = ((unsigned long long)bits << 32)
                              | (unsigned long long)(0xFFFFFFFFu - (unsigned int)i);
            }
        }
    }
    __syncthreads();
    unsigned int n = candCount; if (n > CAND) n = CAND;

    // rank-by-counting: LDS reads of cand[j] are lockstep -> broadcast, conflict-free.
    for (unsigned int i = tid; i < n; i += TOPK_THREADS) {
        unsigned long long ki = cand[i];
        unsigned int rank = 0;
        for (unsigned int j = 0; j < n; ++j)
            rank += (cand[j] > ki) ? 1u : 0u;
        if (rank < (unsigned)K_) sorted[rank] = ki;
    }
    __syncthreads();

    // emit
    float Sf = (float)S;
    float* out_labels = out;
    float* out_boxes  = out + (size_t)B * K_;
    float* out_scores = out + (size_t)B * K_ * 5;
    if (tid < K_) {
        unsigned long long key = sorted[tid];
        unsigned int bits = (unsigned int)(key >> 32);
        unsigned int idx  = 0xFFFFFFFFu - (unsigned int)(key & 0xFFFFFFFFull);
        int label = (int)(idx % C_);
        int q     = (int)(idx / C_);
        const float* bx = boxes_in + ((size_t)b * Q_ + q) * 4;
        float cx = bx[0], cy = bx[1], bw = bx[2], bh = bx[3];
        float x1 = (cx - bw * 0.5f) * Sf;
        float y1 = (cy - bh * 0.5f) * Sf;
        float x2 = (cx + bw * 0.5f) * Sf;
        float y2 = (cy + bh * 0.5f) * Sf;
        int o = b * K_ + tid;
        out_labels[o] = (float)label;
        out_scores[o] = __uint_as_float(bits);
        out_boxes[(size_t)o * 4 + 0] = x1;
        out_boxes[(size_t)o * 4 + 1] = y1;
        out_boxes[(size_t)o * 4 + 2] = x2;
        out_boxes[(size_t)o * 4 + 3] = y2;
        int xi1 = min(max((int)truncf(x1), 0), S);
        int yi1 = min(max((int)truncf(y1), 0), S);
        int xi2 = min(max((int)truncf(x2), 0), S);
        int yi2 = min(max((int)truncf(y2), 0), S);
        meta[(size_t)o * 5 + 0] = q;
        meta[(size_t)o * 5 + 1] = xi1;
        meta[(size_t)o * 5 + 2] = yi1;
        meta[(size_t)o * 5 + 3] = xi2;
        meta[(size_t)o * 5 + 4] = yi2;
    }
}

// -------- Kernel 2 (S=512): 4-row tiles; LDS-staged; XCD-chunked; NT stores; 8 blocks/CU --------
__global__ __launch_bounds__(256, 8) void mask_kernel_512(
    const float* __restrict__ masks,  // [B,Q,HM,WM]
    const int* __restrict__ meta,     // [B*K,5]
    float* __restrict__ out_masks,    // [B*K,512,512]
    int nwork)                        // B*K*128
{
    constexpr int S = 512;
    constexpr float ISC = 0.3125f;  // HM/S exact
    __shared__ float lds[3 * WM];   // up to 3 source rows (4*0.3125 + 2)

    int bid = blockIdx.x;
    int chunk = nwork >> 3;                    // nwork % 8 == 0
    int work = (bid & 7) * chunk + (bid >> 3); // XCD-chunked, bijective
    int bk = work >> 7;
    int yt = work & 127;

    int b = bk / K_;
    const int* m = meta + (size_t)bk * 5;
    int q  = m[0];
    int x1 = m[1], y1 = m[2], x2 = m[3], y2 = m[4];
    const float* src = masks + ((size_t)b * Q_ + q) * (HM * WM);
    float* dst = out_masks + (size_t)bk * S * S;
    int yb0 = yt << 2;  // 4 rows per block

    // Block-level fast path: whole 4-row stripe is zero
    bool stripeLive = (y1 < yb0 + 4) && (y2 > yb0) && (y1 < y2) &&
                      (x1 < x2) && (x1 < S) && (x2 > 0);
    if (!stripeLive) {
        f32x4_t z = (f32x4_t)(0.0f);
        f32x4_t* base2 = reinterpret_cast<f32x4_t*>(dst + (size_t)yb0 * S);
        for (int t = threadIdx.x; t < 4 * 128; t += 256)
            __builtin_nontemporal_store(z, base2 + t);
        return;
    }

    // Stage the needed source rows into LDS (coalesced float4, once per block).
    int fFirst = (int)floorf((yb0 + 0.5f) * ISC - 0.5f);
    int fLast  = (int)floorf((yb0 + 3.5f) * ISC - 0.5f);
    int rowBase = max(fFirst, 0);
    int rowEnd  = min(fLast + 1, HM - 1);
    int nf4 = (rowEnd - rowBase + 1) * (WM / 4);
    {
        const f32x4_t* g4 = reinterpret_cast<const f32x4_t*>(src + (size_t)rowBase * WM);
        f32x4_t* l4 = reinterpret_cast<f32x4_t*>(lds);
        for (int i = threadIdx.x; i < nf4; i += 256) l4[i] = g4[i];
    }
    __syncthreads();

    // 4 rows x 128 float4-chunks; wave-uniform row test, per-lane x-window test
    for (int t = threadIdx.x; t < 4 * 128; t += 256) {
        int ry = t >> 7;
        int xq = t & 127;
        int y  = yb0 + ry;
        int x0 = xq << 2;
        f32x4_t r = (f32x4_t)(0.0f);
        if (y >= y1 && y < y2 && x0 + 4 > x1 && x0 < x2) {
            float iy  = (y + 0.5f) * ISC - 0.5f;
            float fyf = floorf(iy);
            int   y0i = (int)fyf;
            float fy  = iy - fyf;
            int ya = max(y0i, 0);
            int yb = min(y0i + 1, HM - 1);
            const float* r0 = lds + (size_t)(ya - rowBase) * WM;
            const float* r1 = lds + (size_t)(yb - rowBase) * WM;
            float wy0 = 1.0f - fy, wy1 = fy;

            // 3-wide input window shared by the 4 pixels
            float ib  = (x0 + 0.5f) * ISC - 0.5f;
            int   fb  = (int)floorf(ib);
            int i0 = max(fb, 0);
            int i1 = min(fb + 1, WM - 1);
            int i2 = min(fb + 2, WM - 1);
            float a0 = r0[i0], a1 = r0[i1], a2 = r0[i2];
            float b0 = r1[i0], b1 = r1[i1], b2 = r1[i2];

            float v[4];
#pragma unroll
            for (int c = 0; c < 4; ++c) {
                int x = x0 + c;
                float vv = 0.0f;
                if (x >= x1 && x < x2) {
                    float ix  = (x + 0.5f) * ISC - 0.5f;
                    float fxf = floorf(ix);
                    int   x0i = (int)fxf;
                    float fx  = ix - fxf;
                    int o = x0i - fb;           // 0 or 1
                    float va = o ? a1 : a0;
                    float vb = o ? a2 : a1;
                    float wa = o ? b1 : b0;
                    float wb = o ? b2 : b1;
                    float wx0 = 1.0f - fx, wx1 = fx;
                    float top = wx0 * va + wx1 * vb;
                    float bot = wx0 * wa + wx1 * wb;
                    float val = wy0 * top + wy1 * bot;
                    vv = (val > 0.0f) ? 1.0f : 0.0f;
                }
                v[c] = vv;
            }
            r = (f32x4_t){v[0], v[1], v[2], v[3]};
        }
        __builtin_nontemporal_store(r, reinterpret_cast<f32x4_t*>(dst + (size_t)y * S + x0));
    }
}

// -------- Generic fallback (round-1 validated path) --------
__global__ __launch_bounds__(256) void mask_kernel_generic(
    const float* __restrict__ masks,
    const int* __restrict__ meta,
    float* __restrict__ out_masks,
    int S, int rowsPerTile)
{
    int bk = blockIdx.x;
    int ytile = blockIdx.y;
    int b = bk / K_;
    const int* m = meta + (size_t)bk * 5;
    int q  = m[0];
    int x1 = m[1], y1 = m[2], x2 = m[3], y2 = m[4];
    const float* src = masks + ((size_t)b * Q_ + q) * (HM * WM);
    float* dst = out_masks + (size_t)bk * S * S;
    float inv_scale = (float)((double)HM / (double)S);

    int qx = S >> 2;
    int total = rowsPerTile * qx;
    for (int t = threadIdx.x; t < total; t += 256) {
        int ry = t / qx;
        int xq = t - ry * qx;
        int y  = ytile * rowsPerTile + ry;
        int x0 = xq << 2;
        float4 r = make_float4(0.0f, 0.0f, 0.0f, 0.0f);
        if (y >= y1 && y < y2) {
            float iy  = (y + 0.5f) * inv_scale - 0.5f;
            float fyf = floorf(iy);
            int   y0i = (int)fyf;
            float fy  = iy - fyf;
            int ya = max(y0i, 0);
            int yb = min(y0i + 1, HM - 1);
            const float* r0 = src + (size_t)ya * WM;
            const float* r1 = src + (size_t)yb * WM;
            float wy0 = 1.0f - fy, wy1 = fy;
            float v[4];
#pragma unroll
            for (int c = 0; c < 4; ++c) {
                int x = x0 + c;
                float vv = 0.0f;
                if (x >= x1 && x < x2) {
                    float ix  = (x + 0.5f) * inv_scale - 0.5f;
                    float fxf = floorf(ix);
                    int   x0i = (int)fxf;
                    float fx  = ix - fxf;
                    int xa = max(x0i, 0);
                    int xb = min(x0i + 1, WM - 1);
                    float wx0 = 1.0f - fx, wx1 = fx;
                    float top = wx0 * r0[xa] + wx1 * r0[xb];
                    float bot = wx0 * r1[xa] + wx1 * r1[xb];
                    float val = wy0 * top + wy1 * bot;
                    vv = (val > 0.0f) ? 1.0f : 0.0f;
                }
                v[c] = vv;
            }
            r = make_float4(v[0], v[1], v[2], v[3]);
        }
        *reinterpret_cast<float4*>(dst + (size_t)y * S + x0) = r;
    }
}

extern "C" void kernel_launch(void* const* d_in, const int* in_sizes, int n_in,
                              void* d_out, int out_size, void* d_ws, size_t ws_size,
                              hipStream_t stream) {
    const float* pred_logits = (const float*)d_in[0];
    const float* pred_boxes  = (const float*)d_in[1];
    const float* pred_masks  = (const float*)d_in[2];

    int B = in_sizes[0] / QC;
    long long mask_elems = (long long)out_size - (long long)B * K_ * 6;
    int S = (int)llroundf(sqrtf((float)(mask_elems / ((long long)B * K_))));
    if (S <= 0) S = 512;

    float* out = (float*)d_out;
    int* meta = (int*)d_ws;

    topk_kernel<<<dim3(B), dim3(TOPK_THREADS), 0, stream>>>(
        pred_logits, pred_boxes, out, meta, B, S);

    float* out_masks = out + (size_t)B * K_ * 6;
    if (S == 512) {
        int nwork = B * K_ * 128;  // 4-row tiles; divisible by 8
        mask_kernel_512<<<dim3(nwork), dim3(256), 0, stream>>>(
            pred_masks, meta, out_masks, nwork);
    } else {
        int rowsPerTile = 32;
        int ntile = (S + rowsPerTile - 1) / rowsPerTile;
        mask_kernel_generic<<<dim3(B * K_, ntile), dim3(256), 0, stream>>>(
            pred_masks, meta, out_masks, S, rowsPerTile);
    }
}

// Round 16
// 241.336 us; speedup vs baseline: 1.2559x; 1.0367x over previous
//
#include <hip/hip_runtime.h>
#include <cstdint>
#include <cmath>

#define Q_ 300
#define C_ 80
#define QC (Q_ * C_)
#define K_ 300
#define HM 160
#define WM 160
#define NBUCK 8192
#define CAND 2048
#define TOPK_THREADS 512

typedef float f32x4_t __attribute__((ext_vector_type(4)));

// -------- Kernel 1: per-batch top-K over sigmoid(logits) --------
// (round-10 validated: histogram-select + rank-by-counting, vectorized loads)
__global__ __launch_bounds__(TOPK_THREADS) void topk_kernel(
    const float* __restrict__ logits,   // [B,Q,C]
    const float* __restrict__ boxes_in, // [B,Q,4] cxcywh
    float* __restrict__ out,            // labels[B,K] | boxes[B,K,4] | scores[B,K]
    int* __restrict__ meta,             // [B*K,5] : q, x1,y1,x2,y2
    int B, int S)
{
    int b = blockIdx.x;
    int tid = threadIdx.x;
    __shared__ unsigned int hist[NBUCK];
    __shared__ unsigned int csum[TOPK_THREADS];
    __shared__ unsigned long long cand[CAND];
    __shared__ unsigned long long sorted[K_];
    __shared__ unsigned int candCount;
    __shared__ int bstar;

    for (int i = tid; i < NBUCK; i += TOPK_THREADS) hist[i] = 0u;
    if (tid == 0) { candCount = 0u; bstar = 0; }
    __syncthreads();

    const float* lg = logits + (size_t)b * QC;
    const f32x4_t* lg4 = reinterpret_cast<const f32x4_t*>(lg);

    // histogram over top 13 bits of score bit pattern (monotone for positive floats)
    for (int j = tid; j < QC / 4; j += TOPK_THREADS) {
        f32x4_t v4 = lg4[j];
#pragma unroll
        for (int c = 0; c < 4; ++c) {
            float s = 1.0f / (1.0f + expf(-v4[c]));
            unsigned int bits = __float_as_uint(s);
            atomicAdd(&hist[bits >> 19], 1u);
        }
    }
    __syncthreads();

    // per-thread chunk of 16 buckets -> chunk sum
    unsigned int chunkSum = 0u;
    int base = tid * (NBUCK / TOPK_THREADS);
#pragma unroll
    for (int j = 0; j < NBUCK / TOPK_THREADS; ++j) chunkSum += hist[base + j];
    csum[tid] = chunkSum;
    __syncthreads();

    // suffix-inclusive scan: csum[t] = sum_{t'>=t}
    for (int off = 1; off < TOPK_THREADS; off <<= 1) {
        unsigned int v = (tid + off < TOPK_THREADS) ? csum[tid + off] : 0u;
        __syncthreads();
        csum[tid] += v;
        __syncthreads();
    }

    // locate threshold bucket: cumAbove < K <= cumAbove + count
    unsigned int run = (tid < TOPK_THREADS - 1) ? csum[tid + 1] : 0u;
    for (int j = NBUCK / TOPK_THREADS - 1; j >= 0; --j) {
        unsigned int c = hist[base + j];
        if (run < (unsigned)K_ && run + c >= (unsigned)K_) bstar = base + j;  // unique writer
        run += c;
    }
    __syncthreads();
    int bs = bstar;

    // gather candidates; key = score_bits<<32 | (UINT_MAX - idx)
    for (int j = tid; j < QC / 4; j += TOPK_THREADS) {
        f32x4_t v4 = lg4[j];
#pragma unroll
        for (int c = 0; c < 4; ++c) {
            int i = j * 4 + c;
            float s = 1.0f / (1.0f + expf(-v4[c]));
            unsigned int bits = __float_as_uint(s);
            if ((int)(bits >> 19) >= bs) {
                unsigned int pos = atomicAdd(&candCount, 1u);
                if (pos < CAND)
                    cand[pos] = ((unsigned long long)bits << 32)
                              | (unsigned long long)(0xFFFFFFFFu - (unsigned int)i);
            }
        }
    }
    __syncthreads();
    unsigned int n = candCount; if (n > CAND) n = CAND;

    // rank-by-counting: LDS reads of cand[j] are lockstep -> broadcast, conflict-free.
    for (unsigned int i = tid; i < n; i += TOPK_THREADS) {
        unsigned long long ki = cand[i];
        unsigned int rank = 0;
        for (unsigned int j = 0; j < n; ++j)
            rank += (cand[j] > ki) ? 1u : 0u;
        if (rank < (unsigned)K_) sorted[rank] = ki;
    }
    __syncthreads();

    // emit
    float Sf = (float)S;
    float* out_labels = out;
    float* out_boxes  = out + (size_t)B * K_;
    float* out_scores = out + (size_t)B * K_ * 5;
    if (tid < K_) {
        unsigned long long key = sorted[tid];
        unsigned int bits = (unsigned int)(key >> 32);
        unsigned int idx  = 0xFFFFFFFFu - (unsigned int)(key & 0xFFFFFFFFull);
        int label = (int)(idx % C_);
        int q     = (int)(idx / C_);
        const float* bx = boxes_in + ((size_t)b * Q_ + q) * 4;
        float cx = bx[0], cy = bx[1], bw = bx[2], bh = bx[3];
        float x1 = (cx - bw * 0.5f) * Sf;
        float y1 = (cy - bh * 0.5f) * Sf;
        float x2 = (cx + bw * 0.5f) * Sf;
        float y2 = (cy + bh * 0.5f) * Sf;
        int o = b * K_ + tid;
        out_labels[o] = (float)label;
        out_scores[o] = __uint_as_float(bits);
        out_boxes[(size_t)o * 4 + 0] = x1;
        out_boxes[(size_t)o * 4 + 1] = y1;
        out_boxes[(size_t)o * 4 + 2] = x2;
        out_boxes[(size_t)o * 4 + 3] = y2;
        int xi1 = min(max((int)truncf(x1), 0), S);
        int yi1 = min(max((int)truncf(y1), 0), S);
        int xi2 = min(max((int)truncf(x2), 0), S);
        int yi2 = min(max((int)truncf(y2), 0), S);
        meta[(size_t)o * 5 + 0] = q;
        meta[(size_t)o * 5 + 1] = xi1;
        meta[(size_t)o * 5 + 2] = yi1;
        meta[(size_t)o * 5 + 3] = xi2;
        meta[(size_t)o * 5 + 4] = yi2;
    }
}

// -------- Kernel 2 (S=512): 2-row tiles; one chunk/thread; LDS-staged; XCD-chunked; NT stores --------
__global__ __launch_bounds__(256, 8) void mask_kernel_512(
    const float* __restrict__ masks,  // [B,Q,HM,WM]
    const int* __restrict__ meta,     // [B*K,5]
    float* __restrict__ out_masks,    // [B*K,512,512]
    int nwork)                        // B*K*256
{
    constexpr int S = 512;
    constexpr float ISC = 0.3125f;  // HM/S exact
    __shared__ float lds[3 * WM];   // up to 3 source rows

    int bid = blockIdx.x;
    int chunk = nwork >> 3;                    // nwork % 8 == 0
    int work = (bid & 7) * chunk + (bid >> 3); // XCD-chunked, bijective
    int bk = work >> 8;
    int yt = work & 255;

    int b = bk / K_;
    const int* m = meta + (size_t)bk * 5;
    int q  = m[0];
    int x1 = m[1], y1 = m[2], x2 = m[3], y2 = m[4];
    const float* src = masks + ((size_t)b * Q_ + q) * (HM * WM);
    float* dst = out_masks + (size_t)bk * S * S;
    int yb0 = yt << 1;  // 2 rows per block

    // Block-level fast path: whole 2-row stripe is zero
    bool stripeLive = (y1 < yb0 + 2) && (y2 > yb0) && (y1 < y2) &&
                      (x1 < x2) && (x1 < S) && (x2 > 0);
    if (!stripeLive) {
        f32x4_t z = (f32x4_t)(0.0f);
        f32x4_t* base2 = reinterpret_cast<f32x4_t*>(dst + (size_t)yb0 * S);
        __builtin_nontemporal_store(z, base2 + threadIdx.x);
        return;
    }

    // Stage the needed source rows into LDS (coalesced float4, once per block).
    int fFirst = (int)floorf((yb0 + 0.5f) * ISC - 0.5f);
    int fLast  = (int)floorf((yb0 + 1.5f) * ISC - 0.5f);
    int rowBase = max(fFirst, 0);
    int rowEnd  = min(fLast + 1, HM - 1);
    int nf4 = (rowEnd - rowBase + 1) * (WM / 4);
    {
        const f32x4_t* g4 = reinterpret_cast<const f32x4_t*>(src + (size_t)rowBase * WM);
        f32x4_t* l4 = reinterpret_cast<f32x4_t*>(lds);
        if (threadIdx.x < (unsigned)nf4) l4[threadIdx.x] = g4[threadIdx.x];
    }
    __syncthreads();

    // 2 rows x 128 float4-chunks; exactly one chunk per thread
    {
        int t = threadIdx.x;
        int ry = t >> 7;
        int xq = t & 127;
        int y  = yb0 + ry;
        int x0 = xq << 2;
        f32x4_t r = (f32x4_t)(0.0f);
        if (y >= y1 && y < y2 && x0 + 4 > x1 && x0 < x2) {
            float iy  = (y + 0.5f) * ISC - 0.5f;
            float fyf = floorf(iy);
            int   y0i = (int)fyf;
            float fy  = iy - fyf;
            int ya = max(y0i, 0);
            int yb = min(y0i + 1, HM - 1);
            const float* r0 = lds + (size_t)(ya - rowBase) * WM;
            const float* r1 = lds + (size_t)(yb - rowBase) * WM;
            float wy0 = 1.0f - fy, wy1 = fy;

            // 3-wide input window shared by the 4 pixels
            float ib  = (x0 + 0.5f) * ISC - 0.5f;
            int   fb  = (int)floorf(ib);
            int i0 = max(fb, 0);
            int i1 = min(fb + 1, WM - 1);
            int i2 = min(fb + 2, WM - 1);
            float a0 = r0[i0], a1 = r0[i1], a2 = r0[i2];
            float b0 = r1[i0], b1 = r1[i1], b2 = r1[i2];

            float v[4];
#pragma unroll
            for (int c = 0; c < 4; ++c) {
                int x = x0 + c;
                float vv = 0.0f;
                if (x >= x1 && x < x2) {
                    float ix  = (x + 0.5f) * ISC - 0.5f;
                    float fxf = floorf(ix);
                    int   x0i = (int)fxf;
                    float fx  = ix - fxf;
                    int o = x0i - fb;           // 0 or 1
                    float va = o ? a1 : a0;
                    float vb = o ? a2 : a1;
                    float wa = o ? b1 : b0;
                    float wb = o ? b2 : b1;
                    float wx0 = 1.0f - fx, wx1 = fx;
                    float top = wx0 * va + wx1 * vb;
                    float bot = wx0 * wa + wx1 * wb;
                    float val = wy0 * top + wy1 * bot;
                    vv = (val > 0.0f) ? 1.0f : 0.0f;
                }
                v[c] = vv;
            }
            r = (f32x4_t){v[0], v[1], v[2], v[3]};
        }
        __builtin_nontemporal_store(r, reinterpret_cast<f32x4_t*>(dst + (size_t)y * S + x0));
    }
}

// -------- Generic fallback (round-1 validated path) --------
__global__ __launch_bounds__(256) void mask_kernel_generic(
    const float* __restrict__ masks,
    const int* __restrict__ meta,
    float* __restrict__ out_masks,
    int S, int rowsPerTile)
{
    int bk = blockIdx.x;
    int ytile = blockIdx.y;
    int b = bk / K_;
    const int* m = meta + (size_t)bk * 5;
    int q  = m[0];
    int x1 = m[1], y1 = m[2], x2 = m[3], y2 = m[4];
    const float* src = masks + ((size_t)b * Q_ + q) * (HM * WM);
    float* dst = out_masks + (size_t)bk * S * S;
    float inv_scale = (float)((double)HM / (double)S);

    int qx = S >> 2;
    int total = rowsPerTile * qx;
    for (int t = threadIdx.x; t < total; t += 256) {
        int ry = t / qx;
        int xq = t - ry * qx;
        int y  = ytile * rowsPerTile + ry;
        int x0 = xq << 2;
        float4 r = make_float4(0.0f, 0.0f, 0.0f, 0.0f);
        if (y >= y1 && y < y2) {
            float iy  = (y + 0.5f) * inv_scale - 0.5f;
            float fyf = floorf(iy);
            int   y0i = (int)fyf;
            float fy  = iy - fyf;
            int ya = max(y0i, 0);
            int yb = min(y0i + 1, HM - 1);
            const float* r0 = src + (size_t)ya * WM;
            const float* r1 = src + (size_t)yb * WM;
            float wy0 = 1.0f - fy, wy1 = fy;
            float v[4];
#pragma unroll
            for (int c = 0; c < 4; ++c) {
                int x = x0 + c;
                float vv = 0.0f;
                if (x >= x1 && x < x2) {
                    float ix  = (x + 0.5f) * inv_scale - 0.5f;
                    float fxf = floorf(ix);
                    int   x0i = (int)fxf;
                    float fx  = ix - fxf;
                    int xa = max(x0i, 0);
                    int xb = min(x0i + 1, WM - 1);
                    float wx0 = 1.0f - fx, wx1 = fx;
                    float top = wx0 * r0[xa] + wx1 * r0[xb];
                    float bot = wx0 * r1[xa] + wx1 * r1[xb];
                    float val = wy0 * top + wy1 * bot;
                    vv = (val > 0.0f) ? 1.0f : 0.0f;
                }
                v[c] = vv;
            }
            r = make_float4(v[0], v[1], v[2], v[3]);
        }
        *reinterpret_cast<float4*>(dst + (size_t)y * S + x0) = r;
    }
}

extern "C" void kernel_launch(void* const* d_in, const int* in_sizes, int n_in,
                              void* d_out, int out_size, void* d_ws, size_t ws_size,
                              hipStream_t stream) {
    const float* pred_logits = (const float*)d_in[0];
    const float* pred_boxes  = (const float*)d_in[1];
    const float* pred_masks  = (const float*)d_in[2];

    int B = in_sizes[0] / QC;
    long long mask_elems = (long long)out_size - (long long)B * K_ * 6;
    int S = (int)llroundf(sqrtf((float)(mask_elems / ((long long)B * K_))));
    if (S <= 0) S = 512;

    float* out = (float*)d_out;
    int* meta = (int*)d_ws;

    topk_kernel<<<dim3(B), dim3(TOPK_THREADS), 0, stream>>>(
        pred_logits, pred_boxes, out, meta, B, S);

    float* out_masks = out + (size_t)B * K_ * 6;
    if (S == 512) {
        int nwork = B * K_ * 256;  // 2-row tiles; divisible by 8
        mask_kernel_512<<<dim3(nwork), dim3(256), 0, stream>>>(
            pred_masks, meta, out_masks, nwork);
    } else {
        int rowsPerTile = 32;
        int ntile = (S + rowsPerTile - 1) / rowsPerTile;
        mask_kernel_generic<<<dim3(B * K_, ntile), dim3(256), 0, stream>>>(
            pred_masks, meta, out_masks, S, rowsPerTile);
    }
}

// Round 17
// 223.782 us; speedup vs baseline: 1.3545x; 1.0784x over previous
//
#include <hip/hip_runtime.h>
#include <cstdint>
#include <cmath>

#define Q_ 300
#define C_ 80
#define QC (Q_ * C_)
#define K_ 300
#define HM 160
#define WM 160
#define NBUCK 8192
#define CAND 2048
#define TOPK_THREADS 512

typedef float f32x4_t __attribute__((ext_vector_type(4)));

// -------- Kernel 1: per-batch top-K over sigmoid(logits) --------
// (round-10 validated: histogram-select + rank-by-counting, vectorized loads)
__global__ __launch_bounds__(TOPK_THREADS) void topk_kernel(
    const float* __restrict__ logits,   // [B,Q,C]
    const float* __restrict__ boxes_in, // [B,Q,4] cxcywh
    float* __restrict__ out,            // labels[B,K] | boxes[B,K,4] | scores[B,K]
    int* __restrict__ meta,             // [B*K,5] : q, x1,y1,x2,y2
    int B, int S)
{
    int b = blockIdx.x;
    int tid = threadIdx.x;
    __shared__ unsigned int hist[NBUCK];
    __shared__ unsigned int csum[TOPK_THREADS];
    __shared__ unsigned long long cand[CAND];
    __shared__ unsigned long long sorted[K_];
    __shared__ unsigned int candCount;
    __shared__ int bstar;

    for (int i = tid; i < NBUCK; i += TOPK_THREADS) hist[i] = 0u;
    if (tid == 0) { candCount = 0u; bstar = 0; }
    __syncthreads();

    const float* lg = logits + (size_t)b * QC;
    const f32x4_t* lg4 = reinterpret_cast<const f32x4_t*>(lg);

    // histogram over top 13 bits of score bit pattern (monotone for positive floats)
    for (int j = tid; j < QC / 4; j += TOPK_THREADS) {
        f32x4_t v4 = lg4[j];
#pragma unroll
        for (int c = 0; c < 4; ++c) {
            float s = 1.0f / (1.0f + expf(-v4[c]));
            unsigned int bits = __float_as_uint(s);
            atomicAdd(&hist[bits >> 19], 1u);
        }
    }
    __syncthreads();

    // per-thread chunk of 16 buckets -> chunk sum
    unsigned int chunkSum = 0u;
    int base = tid * (NBUCK / TOPK_THREADS);
#pragma unroll
    for (int j = 0; j < NBUCK / TOPK_THREADS; ++j) chunkSum += hist[base + j];
    csum[tid] = chunkSum;
    __syncthreads();

    // suffix-inclusive scan: csum[t] = sum_{t'>=t}
    for (int off = 1; off < TOPK_THREADS; off <<= 1) {
        unsigned int v = (tid + off < TOPK_THREADS) ? csum[tid + off] : 0u;
        __syncthreads();
        csum[tid] += v;
        __syncthreads();
    }

    // locate threshold bucket: cumAbove < K <= cumAbove + count
    unsigned int run = (tid < TOPK_THREADS - 1) ? csum[tid + 1] : 0u;
    for (int j = NBUCK / TOPK_THREADS - 1; j >= 0; --j) {
        unsigned int c = hist[base + j];
        if (run < (unsigned)K_ && run + c >= (unsigned)K_) bstar = base + j;  // unique writer
        run += c;
    }
    __syncthreads();
    int bs = bstar;

    // gather candidates; key = score_bits<<32 | (UINT_MAX - idx)
    for (int j = tid; j < QC / 4; j += TOPK_THREADS) {
        f32x4_t v4 = lg4[j];
#pragma unroll
        for (int c = 0; c < 4; ++c) {
            int i = j * 4 + c;
            float s = 1.0f / (1.0f + expf(-v4[c]));
            unsigned int bits = __float_as_uint(s);
            if ((int)(bits >> 19) >= bs) {
                unsigned int pos = atomicAdd(&candCount, 1u);
                if (pos < CAND)
                    cand[pos] = ((unsigned long long)bits << 32)
                              | (unsigned long long)(0xFFFFFFFFu - (unsigned int)i);
            }
        }
    }
    __syncthreads();
    unsigned int n = candCount; if (n > CAND) n = CAND;

    // rank-by-counting: LDS reads of cand[j] are lockstep -> broadcast, conflict-free.
    for (unsigned int i = tid; i < n; i += TOPK_THREADS) {
        unsigned long long ki = cand[i];
        unsigned int rank = 0;
        for (unsigned int j = 0; j < n; ++j)
            rank += (cand[j] > ki) ? 1u : 0u;
        if (rank < (unsigned)K_) sorted[rank] = ki;
    }
    __syncthreads();

    // emit
    float Sf = (float)S;
    float* out_labels = out;
    float* out_boxes  = out + (size_t)B * K_;
    float* out_scores = out + (size_t)B * K_ * 5;
    if (tid < K_) {
        unsigned long long key = sorted[tid];
        unsigned int bits = (unsigned int)(key >> 32);
        unsigned int idx  = 0xFFFFFFFFu - (unsigned int)(key & 0xFFFFFFFFull);
        int label = (int)(idx % C_);
        int q     = (int)(idx / C_);
        const float* bx = boxes_in + ((size_t)b * Q_ + q) * 4;
        float cx = bx[0], cy = bx[1], bw = bx[2], bh = bx[3];
        float x1 = (cx - bw * 0.5f) * Sf;
        float y1 = (cy - bh * 0.5f) * Sf;
        float x2 = (cx + bw * 0.5f) * Sf;
        float y2 = (cy + bh * 0.5f) * Sf;
        int o = b * K_ + tid;
        out_labels[o] = (float)label;
        out_scores[o] = __uint_as_float(bits);
        out_boxes[(size_t)o * 4 + 0] = x1;
        out_boxes[(size_t)o * 4 + 1] = y1;
        out_boxes[(size_t)o * 4 + 2] = x2;
        out_boxes[(size_t)o * 4 + 3] = y2;
        int xi1 = min(max((int)truncf(x1), 0), S);
        int yi1 = min(max((int)truncf(y1), 0), S);
        int xi2 = min(max((int)truncf(x2), 0), S);
        int yi2 = min(max((int)truncf(y2), 0), S);
        meta[(size_t)o * 5 + 0] = q;
        meta[(size_t)o * 5 + 1] = xi1;
        meta[(size_t)o * 5 + 2] = yi1;
        meta[(size_t)o * 5 + 3] = xi2;
        meta[(size_t)o * 5 + 4] = yi2;
    }
}

// -------- Kernel 2 (S=512): 1-row tiles; 128 thr; one chunk/thread; LDS-staged; XCD-chunked; NT --------
__global__ __launch_bounds__(128, 8) void mask_kernel_512(
    const float* __restrict__ masks,  // [B,Q,HM,WM]
    const int* __restrict__ meta,     // [B*K,5]
    float* __restrict__ out_masks,    // [B*K,512,512]
    int nwork)                        // B*K*512
{
    constexpr int S = 512;
    constexpr float ISC = 0.3125f;  // HM/S exact
    __shared__ float lds[2 * WM];   // exactly <=2 source rows per output row

    int bid = blockIdx.x;
    int chunk = nwork >> 3;                    // nwork % 8 == 0
    int work = (bid & 7) * chunk + (bid >> 3); // XCD-chunked, bijective
    int bk = work >> 9;
    int y  = work & 511;                       // one output row per block

    int b = bk / K_;
    const int* m = meta + (size_t)bk * 5;
    int q  = m[0];
    int x1 = m[1], y1 = m[2], x2 = m[3], y2 = m[4];
    const float* src = masks + ((size_t)b * Q_ + q) * (HM * WM);
    float* dst = out_masks + (size_t)bk * S * S + (size_t)y * S;

    // Row-level fast path (block-uniform)
    bool rowLive = (y >= y1) && (y < y2) && (x1 < x2) && (x1 < S) && (x2 > 0);
    if (!rowLive) {
        f32x4_t z = (f32x4_t)(0.0f);
        __builtin_nontemporal_store(z, reinterpret_cast<f32x4_t*>(dst) + threadIdx.x);
        return;
    }

    // y interp setup (block-uniform)
    float iy  = (y + 0.5f) * ISC - 0.5f;
    float fyf = floorf(iy);
    int   y0i = (int)fyf;
    float fy  = iy - fyf;
    int ya = max(y0i, 0);
    int yb = min(y0i + 1, HM - 1);
    float wy0 = 1.0f - fy, wy1 = fy;

    // Stage the two needed source rows into LDS (ya -> lds[0..], yb -> lds[WM..])
    {
        const f32x4_t* gA = reinterpret_cast<const f32x4_t*>(src + (size_t)ya * WM);
        const f32x4_t* gB = reinterpret_cast<const f32x4_t*>(src + (size_t)yb * WM);
        f32x4_t* l4 = reinterpret_cast<f32x4_t*>(lds);
        int t = threadIdx.x;
        if (t < WM / 4) l4[t] = gA[t];
        else if (t < 2 * (WM / 4)) l4[t] = gB[t - WM / 4];
    }
    __syncthreads();
    const float* r0 = lds;
    const float* r1 = lds + WM;

    // one float4 chunk per thread
    {
        int xq = threadIdx.x;
        int x0 = xq << 2;
        f32x4_t r = (f32x4_t)(0.0f);
        if (x0 + 4 > x1 && x0 < x2) {
            // 3-wide input window shared by the 4 pixels
            float ib  = (x0 + 0.5f) * ISC - 0.5f;
            int   fb  = (int)floorf(ib);
            int i0 = max(fb, 0);
            int i1 = min(fb + 1, WM - 1);
            int i2 = min(fb + 2, WM - 1);
            float a0 = r0[i0], a1 = r0[i1], a2 = r0[i2];
            float b0 = r1[i0], b1 = r1[i1], b2 = r1[i2];

            float v[4];
#pragma unroll
            for (int c = 0; c < 4; ++c) {
                int x = x0 + c;
                float vv = 0.0f;
                if (x >= x1 && x < x2) {
                    float ix  = (x + 0.5f) * ISC - 0.5f;
                    float fxf = floorf(ix);
                    int   x0i = (int)fxf;
                    float fx  = ix - fxf;
                    int o = x0i - fb;           // 0 or 1
                    float va = o ? a1 : a0;
                    float vb = o ? a2 : a1;
                    float wa = o ? b1 : b0;
                    float wb = o ? b2 : b1;
                    float wx0 = 1.0f - fx, wx1 = fx;
                    float top = wx0 * va + wx1 * vb;
                    float bot = wx0 * wa + wx1 * wb;
                    float val = wy0 * top + wy1 * bot;
                    vv = (val > 0.0f) ? 1.0f : 0.0f;
                }
                v[c] = vv;
            }
            r = (f32x4_t){v[0], v[1], v[2], v[3]};
        }
        __builtin_nontemporal_store(r, reinterpret_cast<f32x4_t*>(dst) + xq);
    }
}

// -------- Generic fallback (round-1 validated path) --------
__global__ __launch_bounds__(256) void mask_kernel_generic(
    const float* __restrict__ masks,
    const int* __restrict__ meta,
    float* __restrict__ out_masks,
    int S, int rowsPerTile)
{
    int bk = blockIdx.x;
    int ytile = blockIdx.y;
    int b = bk / K_;
    const int* m = meta + (size_t)bk * 5;
    int q  = m[0];
    int x1 = m[1], y1 = m[2], x2 = m[3], y2 = m[4];
    const float* src = masks + ((size_t)b * Q_ + q) * (HM * WM);
    float* dst = out_masks + (size_t)bk * S * S;
    float inv_scale = (float)((double)HM / (double)S);

    int qx = S >> 2;
    int total = rowsPerTile * qx;
    for (int t = threadIdx.x; t < total; t += 256) {
        int ry = t / qx;
        int xq = t - ry * qx;
        int y  = ytile * rowsPerTile + ry;
        int x0 = xq << 2;
        float4 r = make_float4(0.0f, 0.0f, 0.0f, 0.0f);
        if (y >= y1 && y < y2) {
            float iy  = (y + 0.5f) * inv_scale - 0.5f;
            float fyf = floorf(iy);
            int   y0i = (int)fyf;
            float fy  = iy - fyf;
            int ya = max(y0i, 0);
            int yb = min(y0i + 1, HM - 1);
            const float* r0 = src + (size_t)ya * WM;
            const float* r1 = src + (size_t)yb * WM;
            float wy0 = 1.0f - fy, wy1 = fy;
            float v[4];
#pragma unroll
            for (int c = 0; c < 4; ++c) {
                int x = x0 + c;
                float vv = 0.0f;
                if (x >= x1 && x < x2) {
                    float ix  = (x + 0.5f) * inv_scale - 0.5f;
                    float fxf = floorf(ix);
                    int   x0i = (int)fxf;
                    float fx  = ix - fxf;
                    int xa = max(x0i, 0);
                    int xb = min(x0i + 1, WM - 1);
                    float wx0 = 1.0f - fx, wx1 = fx;
                    float top = wx0 * r0[xa] + wx1 * r0[xb];
                    float bot = wx0 * r1[xa] + wx1 * r1[xb];
                    float val = wy0 * top + wy1 * bot;
                    vv = (val > 0.0f) ? 1.0f : 0.0f;
                }
                v[c] = vv;
            }
            r = make_float4(v[0], v[1], v[2], v[3]);
        }
        *reinterpret_cast<float4*>(dst + (size_t)y * S + x0) = r;
    }
}

extern "C" void kernel_launch(void* const* d_in, const int* in_sizes, int n_in,
                              void* d_out, int out_size, void* d_ws, size_t ws_size,
                              hipStream_t stream) {
    const float* pred_logits = (const float*)d_in[0];
    const float* pred_boxes  = (const float*)d_in[1];
    const float* pred_masks  = (const float*)d_in[2];

    int B = in_sizes[0] / QC;
    long long mask_elems = (long long)out_size - (long long)B * K_ * 6;
    int S = (int)llroundf(sqrtf((float)(mask_elems / ((long long)B * K_))));
    if (S <= 0) S = 512;

    float* out = (float*)d_out;
    int* meta = (int*)d_ws;

    topk_kernel<<<dim3(B), dim3(TOPK_THREADS), 0, stream>>>(
        pred_logits, pred_boxes, out, meta, B, S);

    float* out_masks = out + (size_t)B * K_ * 6;
    if (S == 512) {
        int nwork = B * K_ * 512;  // 1-row tiles; divisible by 8
        mask_kernel_512<<<dim3(nwork), dim3(128), 0, stream>>>(
            pred_masks, meta, out_masks, nwork);
    } else {
        int rowsPerTile = 32;
        int ntile = (S + rowsPerTile - 1) / rowsPerTile;
        mask_kernel_generic<<<dim3(B * K_, ntile), dim3(256), 0, stream>>>(
            pred_masks, meta, out_masks, S, rowsPerTile);
    }
}